// Round 1
// baseline (7301.822 us; speedup 1.0000x reference)
//
#include <hip/hip_runtime.h>
#include <math.h>

#define DEV static __device__ __forceinline__

DEV float hsum4(const float4 v) { return (v.x + v.y) + (v.z + v.w); }
DEV float4 zero4() { return make_float4(0.f, 0.f, 0.f, 0.f); }
DEV void fma4(float4& a, const float4 x, const float4 w) {
  a.x = fmaf(x.x, w.x, a.x); a.y = fmaf(x.y, w.y, a.y);
  a.z = fmaf(x.z, w.z, a.z); a.w = fmaf(x.w, w.w, a.w);
}

// pair-row x col-quad register tile:
// rows (i0, i0+17), cols {row0 + step*q}, K = 4*KF4, inputs via float4 LDS reads
template <int KF4>
DEV void pair_tile(const float4* __restrict__ Xf, int xs4, int i0,
                   const float4* __restrict__ Wf, int ws4, int row0, int step,
                   float4* a0, float4* a1) {
#pragma unroll
  for (int q = 0; q < 4; ++q) { a0[q] = zero4(); a1[q] = zero4(); }
#pragma unroll
  for (int k4 = 0; k4 < KF4; ++k4) {
    float4 za = Xf[i0 * xs4 + k4];
    float4 zb = Xf[(i0 + 17) * xs4 + k4];
#pragma unroll
    for (int q = 0; q < 4; ++q) {
      float4 w = Wf[(row0 + step * q) * ws4 + k4];
      fma4(a0[q], za, w);
      fma4(a1[q], zb, w);
    }
  }
}

// ---------------- prep: A = -(B^T B), tau1_w repack ----------------
__global__ __launch_bounds__(64) void prep_kernel(
    const float* __restrict__ Bm, const float* __restrict__ tau1_w,
    float* __restrict__ A, float* __restrict__ t1wp, float* __restrict__ t1t) {
  const int t = threadIdx.x, blk = blockIdx.x;
  if (blk < 64) {
    float acc = 0.f;
    for (int k = 0; k < 64; ++k)
      acc = fmaf(Bm[k * 64 + blk], Bm[k * 64 + t], acc);
    A[blk * 64 + t] = -acc;
  } else {
    int base = (blk - 64) * 64 + t;  // 0..255
    for (int idx = base; idx < 8192; idx += 256) {
      int j = idx >> 6, k = idx & 63;
      t1wp[idx] = tau1_w[j * 65 + k];
    }
    if (base < 128) t1t[base] = tau1_w[base * 65 + 64];
  }
}

// ---------------- transformer: patch embed + 3 layers, 1 block per batch ----------------
// LDS carve (floats): Z[0,2312)=34x68 | QKV[2312,8976)=34x196 | R3[8976,13332)=4356
// (scores 132x33 / weight-stage 64x68 / f1 34x100) | R4[13332,15644)=34x68 (o) | lnm/lnr
__global__ __launch_bounds__(256) void tf_kernel(
    const float* __restrict__ x,
    const float* __restrict__ conv_w, const float* __restrict__ conv_b,
    const float* __restrict__ cls,
    const float* __restrict__ attn_w, const float* __restrict__ attn_b,
    const float* __restrict__ out_w, const float* __restrict__ out_b,
    const float* __restrict__ ln1_g, const float* __restrict__ ln1_b,
    const float* __restrict__ ln2_g, const float* __restrict__ ln2_b,
    const float* __restrict__ ff1_w, const float* __restrict__ ff1_b,
    const float* __restrict__ ff2_w, const float* __restrict__ ff2_b,
    float* __restrict__ zc) {
  __shared__ float L[15712];
  float* Z = L;
  float* QKV = L + 2312;
  float* R3 = L + 8976;
  float* R4 = L + 13332;
  float* lnm = L + 15644;
  float* lnr = L + 15678;
  float4* Zf = (float4*)Z;
  float4* QKVf = (float4*)QKV;
  float4* R3f = (float4*)R3;
  float4* R4f = (float4*)R4;

  const int t = threadIdx.x;
  const int b = blockIdx.x;

  // stage conv_w transposed [d][p][c] into QKV region (dead during patch phase)
  float* CW = QKV;
  for (int idx = t; idx < 8192; idx += 256) {
    int d = idx >> 7, r = idx & 127;
    CW[d * 128 + (r & 15) * 8 + (r >> 4)] = conv_w[idx];
  }
  __syncthreads();

  // patch embed + positional encoding
  {
    const int n = t & 31, dg = t >> 5;  // patch, d-group of 8
    const float4* xg = (const float4*)(x + (size_t)b * 4096);
    const float4* cw4 = (const float4*)CW;
    float4 acc[8];
#pragma unroll
    for (int dd = 0; dd < 8; ++dd) acc[dd] = zero4();
    for (int p = 0; p < 16; ++p) {
      float4 xa = xg[(n * 16 + p) * 2 + 0];
      float4 xb = xg[(n * 16 + p) * 2 + 1];
#pragma unroll
      for (int dd = 0; dd < 8; ++dd) {
        int base = (dg * 8 + dd) * 32 + p * 2;
        fma4(acc[dd], xa, cw4[base]);
        fma4(acc[dd], xb, cw4[base + 1]);
      }
    }
#pragma unroll
    for (int dd = 0; dd < 8; ++dd) {
      int d = dg * 8 + dd;
      float v = hsum4(acc[dd]) + conv_b[d];
      float freq = expf(-0.14391157f * (float)(d & ~1));  // ln(1e4)/64
      float ang = (float)(n + 1) * freq;
      v += (d & 1) ? cosf(ang) : sinf(ang);
      Z[(n + 1) * 68 + d] = v;
    }
  }
  if (t < 64) Z[t] = cls[t] + ((t & 1) ? 1.0f : 0.0f);  // pe(0,odd)=1
  if (t >= 64 && t < 132) Z[33 * 68 + (t - 64)] = 0.0f; // zero fake row 33
  __syncthreads();

  for (int l = 0; l < 3; ++l) {
    const float* AW = attn_w + l * 12288;
    const float* AB = attn_b + l * 192;

    // ---- qkv = z @ aw^T + b, 3 chunks of 64 output cols (weights staged) ----
    for (int c = 0; c < 3; ++c) {
      const float4* awf = (const float4*)(AW + c * 4096);
      for (int i4 = t; i4 < 1024; i4 += 256)
        R3f[(i4 >> 4) * 17 + (i4 & 15)] = awf[i4];
      __syncthreads();
      for (int tile = t; tile < 272; tile += 256) {
        int i0 = tile >> 4, j4 = tile & 15;
        float4 a0[4], a1[4];
        pair_tile<16>(Zf, 17, i0, R3f, 17, j4, 16, a0, a1);
#pragma unroll
        for (int q = 0; q < 4; ++q) {
          int j = c * 64 + j4 + 16 * q;
          float bias = AB[j];
          QKV[i0 * 196 + j] = hsum4(a0[q]) + bias;
          QKV[(i0 + 17) * 196 + j] = hsum4(a1[q]) + bias;
        }
      }
      __syncthreads();
    }

    // ---- scores = 0.25 * q k^T per head ----
    for (int idx = t; idx < 4356; idx += 256) {
      int r = idx / 33, kk = idx - r * 33;
      int h = r / 33, i = r - h * 33;
      float4 acc = zero4();
#pragma unroll
      for (int dq = 0; dq < 4; ++dq)
        fma4(acc, QKVf[i * 49 + h * 4 + dq], QKVf[kk * 49 + 16 + h * 4 + dq]);
      R3[r * 33 + kk] = 0.25f * hsum4(acc);
    }
    __syncthreads();

    // ---- softmax over kk (one thread per (h,i) row) ----
    if (t < 132) {
      float* s = R3 + t * 33;
      float mx = s[0];
      for (int kk = 1; kk < 33; ++kk) mx = fmaxf(mx, s[kk]);
      float sum = 0.f;
      for (int kk = 0; kk < 33; ++kk) { float e = expf(s[kk] - mx); s[kk] = e; sum += e; }
      float inv = 1.f / sum;
      for (int kk = 0; kk < 33; ++kk) s[kk] *= inv;
    }
    __syncthreads();

    // ---- o = att @ v ----
    for (int idx = t; idx < 528; idx += 256) {
      int i = idx >> 4, d4 = idx & 15, h = d4 >> 2;
      const float* srow = R3 + (h * 33 + i) * 33;
      float4 acc = zero4();
      for (int kk = 0; kk < 33; ++kk) {
        float a = srow[kk];
        float4 v4 = QKVf[kk * 49 + 32 + d4];
        acc.x = fmaf(a, v4.x, acc.x); acc.y = fmaf(a, v4.y, acc.y);
        acc.z = fmaf(a, v4.z, acc.z); acc.w = fmaf(a, v4.w, acc.w);
      }
      R4f[i * 17 + d4] = acc;
    }
    if (t < 17) R4f[33 * 17 + t] = zero4();  // zero fake o row
    __syncthreads();

    // ---- stage out_w ----
    {
      const float4* owf = (const float4*)(out_w + l * 4096);
      for (int i4 = t; i4 < 1024; i4 += 256)
        R3f[(i4 >> 4) * 17 + (i4 & 15)] = owf[i4];
    }
    __syncthreads();

    // ---- z += o @ out_w^T + b ----
    for (int tile = t; tile < 272; tile += 256) {
      int i0 = tile >> 4, d4 = tile & 15;
      float4 a0[4], a1[4];
      pair_tile<16>(R4f, 17, i0, R3f, 17, d4, 16, a0, a1);
#pragma unroll
      for (int q = 0; q < 4; ++q) {
        int d = d4 + 16 * q;
        float bias = out_b[l * 64 + d];
        Z[i0 * 68 + d] += hsum4(a0[q]) + bias;
        Z[(i0 + 17) * 68 + d] += hsum4(a1[q]) + bias;
      }
    }
    __syncthreads();

    // ---- LN1 ----
    if (t < 33) {
      const float4* zr = (const float4*)(Z + t * 68);
      float4 s4 = zero4(), q4 = zero4();
      for (int k4 = 0; k4 < 16; ++k4) {
        float4 v = zr[k4];
        s4.x += v.x; s4.y += v.y; s4.z += v.z; s4.w += v.w;
        q4.x = fmaf(v.x, v.x, q4.x); q4.y = fmaf(v.y, v.y, q4.y);
        q4.z = fmaf(v.z, v.z, q4.z); q4.w = fmaf(v.w, v.w, q4.w);
      }
      float m = hsum4(s4) * 0.015625f;
      float var = hsum4(q4) * 0.015625f - m * m;
      lnm[t] = m; lnr[t] = rsqrtf(var + 1e-5f);
    }
    __syncthreads();
    for (int idx = t; idx < 2112; idx += 256) {
      int i = idx >> 6, d = idx & 63;
      Z[i * 68 + d] = (Z[i * 68 + d] - lnm[i]) * lnr[i] * ln1_g[l * 64 + d] + ln1_b[l * 64 + d];
    }
    __syncthreads();

    // ---- stage ff1_w (96x64) ----
    {
      const float4* wf = (const float4*)(ff1_w + l * 6144);
      for (int i4 = t; i4 < 1536; i4 += 256)
        QKVf[(i4 >> 4) * 17 + (i4 & 15)] = wf[i4];
    }
    __syncthreads();

    // ---- f1 = relu(z @ ff1^T + b) ----
    for (int tile = t; tile < 408; tile += 256) {
      int i0 = tile / 24, j4 = tile - i0 * 24;
      float4 a0[4], a1[4];
      pair_tile<16>(Zf, 17, i0, QKVf, 17, j4, 24, a0, a1);
#pragma unroll
      for (int q = 0; q < 4; ++q) {
        int j = j4 + 24 * q;
        float bias = ff1_b[l * 96 + j];
        R3[i0 * 100 + j] = fmaxf(hsum4(a0[q]) + bias, 0.f);
        R3[(i0 + 17) * 100 + j] = fmaxf(hsum4(a1[q]) + bias, 0.f);
      }
    }
    __syncthreads();

    // ---- stage ff2_w (64x96), row stride 100 ----
    {
      const float4* wf = (const float4*)(ff2_w + l * 6144);
      for (int i4 = t; i4 < 1536; i4 += 256) {
        int row = i4 / 24, k4 = i4 - row * 24;
        QKVf[row * 25 + k4] = wf[i4];
      }
    }
    __syncthreads();

    // ---- z += f1 @ ff2^T + b ----
    for (int tile = t; tile < 272; tile += 256) {
      int i0 = tile >> 4, d4 = tile & 15;
      float4 a0[4], a1[4];
      pair_tile<24>(R3f, 25, i0, QKVf, 25, d4, 16, a0, a1);
#pragma unroll
      for (int q = 0; q < 4; ++q) {
        int d = d4 + 16 * q;
        float bias = ff2_b[l * 64 + d];
        Z[i0 * 68 + d] += hsum4(a0[q]) + bias;
        Z[(i0 + 17) * 68 + d] += hsum4(a1[q]) + bias;
      }
    }
    __syncthreads();

    // ---- LN2 ----
    if (t < 33) {
      const float4* zr = (const float4*)(Z + t * 68);
      float4 s4 = zero4(), q4 = zero4();
      for (int k4 = 0; k4 < 16; ++k4) {
        float4 v = zr[k4];
        s4.x += v.x; s4.y += v.y; s4.z += v.z; s4.w += v.w;
        q4.x = fmaf(v.x, v.x, q4.x); q4.y = fmaf(v.y, v.y, q4.y);
        q4.z = fmaf(v.z, v.z, q4.z); q4.w = fmaf(v.w, v.w, q4.w);
      }
      float m = hsum4(s4) * 0.015625f;
      float var = hsum4(q4) * 0.015625f - m * m;
      lnm[t] = m; lnr[t] = rsqrtf(var + 1e-5f);
    }
    __syncthreads();
    for (int idx = t; idx < 2112; idx += 256) {
      int i = idx >> 6, d = idx & 63;
      Z[i * 68 + d] = (Z[i * 68 + d] - lnm[i]) * lnr[i] * ln2_g[l * 64 + d] + ln2_b[l * 64 + d];
    }
    __syncthreads();
  }

  if (t < 64) zc[(size_t)b * 64 + t] = Z[t];  // cls token
}

// ---------------- ODE (32 Euler steps) + final FC: 16 batch rows per block ----------------
__global__ __launch_bounds__(512) void ode_kernel(
    const float* __restrict__ zc,
    const float* __restrict__ dr1_w, const float* __restrict__ dr1_b,
    const float* __restrict__ dr2_w, const float* __restrict__ dr2_b,
    const float* __restrict__ t1wp, const float* __restrict__ t1t,
    const float* __restrict__ tau1_b,
    const float* __restrict__ tau2_w, const float* __restrict__ tau2_b,
    const float* __restrict__ A,
    const float* __restrict__ fc_w, const float* __restrict__ fc_b,
    float* __restrict__ out) {
  __shared__ float ZT[16 * 68];
  __shared__ float HID[16 * 132];
  __shared__ float DRV[16 * 68];
  __shared__ float TAU[16 * 68];
  __shared__ float ZA[16 * 68];
  float4* ZTf = (float4*)ZT;
  float4* HIDf = (float4*)HID;

  const int t = threadIdx.x;
  const int b0 = blockIdx.x * 16;

  if (t < 256) ZTf[(t >> 4) * 17 + (t & 15)] = ((const float4*)(zc + (size_t)b0 * 64))[t];
  __syncthreads();

  const int bb = t >> 5;  // 0..15 batch row
  const int j4 = t & 31;  // 0..31
  float tm = 0.f;

  for (int s = 0; s < 32; ++s) {
    // hidden_drive = tanh(zt @ dr1^T + b): cols {j4 + 32q}
    {
      const float4* w = (const float4*)dr1_w;
      float4 a0 = zero4(), a1 = zero4(), a2 = zero4(), a3 = zero4();
      for (int k4 = 0; k4 < 16; ++k4) {
        float4 z4 = ZTf[bb * 17 + k4];
        fma4(a0, z4, w[(j4) * 16 + k4]);
        fma4(a1, z4, w[(j4 + 32) * 16 + k4]);
        fma4(a2, z4, w[(j4 + 64) * 16 + k4]);
        fma4(a3, z4, w[(j4 + 96) * 16 + k4]);
      }
      HID[bb * 132 + j4] = tanhf(hsum4(a0) + dr1_b[j4]);
      HID[bb * 132 + j4 + 32] = tanhf(hsum4(a1) + dr1_b[j4 + 32]);
      HID[bb * 132 + j4 + 64] = tanhf(hsum4(a2) + dr1_b[j4 + 64]);
      HID[bb * 132 + j4 + 96] = tanhf(hsum4(a3) + dr1_b[j4 + 96]);
    }
    __syncthreads();
    // drive = hid @ dr2^T + b ; zA = zt @ A^T : cols {j4, j4+32}
    {
      const float4* w = (const float4*)dr2_w;
      float4 a0 = zero4(), a1 = zero4();
      for (int k4 = 0; k4 < 32; ++k4) {
        float4 h4 = HIDf[bb * 33 + k4];
        fma4(a0, h4, w[(j4) * 32 + k4]);
        fma4(a1, h4, w[(j4 + 32) * 32 + k4]);
      }
      const float4* af = (const float4*)A;
      float4 g0 = zero4(), g1 = zero4();
      for (int k4 = 0; k4 < 16; ++k4) {
        float4 z4 = ZTf[bb * 17 + k4];
        fma4(g0, z4, af[(j4) * 16 + k4]);
        fma4(g1, z4, af[(j4 + 32) * 16 + k4]);
      }
      DRV[bb * 68 + j4] = hsum4(a0) + dr2_b[j4];
      DRV[bb * 68 + j4 + 32] = hsum4(a1) + dr2_b[j4 + 32];
      ZA[bb * 68 + j4] = hsum4(g0);
      ZA[bb * 68 + j4 + 32] = hsum4(g1);
    }
    __syncthreads();
    // hidden_tau = tanh([zt,t] @ tau1^T + b)
    {
      const float4* w = (const float4*)t1wp;
      float4 a0 = zero4(), a1 = zero4(), a2 = zero4(), a3 = zero4();
      for (int k4 = 0; k4 < 16; ++k4) {
        float4 z4 = ZTf[bb * 17 + k4];
        fma4(a0, z4, w[(j4) * 16 + k4]);
        fma4(a1, z4, w[(j4 + 32) * 16 + k4]);
        fma4(a2, z4, w[(j4 + 64) * 16 + k4]);
        fma4(a3, z4, w[(j4 + 96) * 16 + k4]);
      }
      HID[bb * 132 + j4] = tanhf(hsum4(a0) + fmaf(tm, t1t[j4], tau1_b[j4]));
      HID[bb * 132 + j4 + 32] = tanhf(hsum4(a1) + fmaf(tm, t1t[j4 + 32], tau1_b[j4 + 32]));
      HID[bb * 132 + j4 + 64] = tanhf(hsum4(a2) + fmaf(tm, t1t[j4 + 64], tau1_b[j4 + 64]));
      HID[bb * 132 + j4 + 96] = tanhf(hsum4(a3) + fmaf(tm, t1t[j4 + 96], tau1_b[j4 + 96]));
    }
    __syncthreads();
    // tau_raw = hid @ tau2^T + b
    {
      const float4* w = (const float4*)tau2_w;
      float4 a0 = zero4(), a1 = zero4();
      for (int k4 = 0; k4 < 32; ++k4) {
        float4 h4 = HIDf[bb * 33 + k4];
        fma4(a0, h4, w[(j4) * 32 + k4]);
        fma4(a1, h4, w[(j4 + 32) * 32 + k4]);
      }
      TAU[bb * 68 + j4] = hsum4(a0) + tau2_b[j4];
      TAU[bb * 68 + j4 + 32] = hsum4(a1) + tau2_b[j4 + 32];
    }
    __syncthreads();
    // combine: zt += h * (zA + inv*(drive - zt))
    for (int idx = t; idx < 1024; idx += 512) {
      int bi = idx >> 6, d = idx & 63;
      float ztv = ZT[bi * 68 + d];
      float traw = TAU[bi * 68 + d];
      float sp = (traw > 15.f) ? traw : log1pf(expf(traw));
      float sg = 1.f / (1.f + expf(-(sp + 1e-6f)));
      float tau = fmaf(4.95f, sg, 0.05f);
      float inv = 1.f / tau;
      float dz = ZA[bi * 68 + d] + inv * (DRV[bi * 68 + d] - ztv);
      ZT[bi * 68 + d] = fmaf(0.03125f, dz, ztv);
    }
    __syncthreads();
    tm += 0.03125f;
  }

  // final FC: out[b][192]
  for (int idx = t; idx < 768; idx += 512) {
    int bi = idx / 48, qd = idx - bi * 48;
    const float4* w = (const float4*)fc_w;
    float4 a0 = zero4(), a1 = zero4(), a2 = zero4(), a3 = zero4();
    for (int k4 = 0; k4 < 16; ++k4) {
      float4 z4 = ZTf[bi * 17 + k4];
      fma4(a0, z4, w[(qd * 4 + 0) * 16 + k4]);
      fma4(a1, z4, w[(qd * 4 + 1) * 16 + k4]);
      fma4(a2, z4, w[(qd * 4 + 2) * 16 + k4]);
      fma4(a3, z4, w[(qd * 4 + 3) * 16 + k4]);
    }
    float4 r;
    r.x = hsum4(a0) + fc_b[qd * 4 + 0];
    r.y = hsum4(a1) + fc_b[qd * 4 + 1];
    r.z = hsum4(a2) + fc_b[qd * 4 + 2];
    r.w = hsum4(a3) + fc_b[qd * 4 + 3];
    ((float4*)(out + (size_t)(b0 + bi) * 192))[qd] = r;
  }
}

extern "C" void kernel_launch(void* const* d_in, const int* in_sizes, int n_in,
                              void* d_out, int out_size, void* d_ws, size_t ws_size,
                              hipStream_t stream) {
  const float* x = (const float*)d_in[0];
  const float* conv_w = (const float*)d_in[1];
  const float* conv_b = (const float*)d_in[2];
  const float* cls = (const float*)d_in[3];
  const float* attn_w = (const float*)d_in[4];
  const float* attn_b = (const float*)d_in[5];
  const float* out_w = (const float*)d_in[6];
  const float* out_b = (const float*)d_in[7];
  const float* ln1_g = (const float*)d_in[8];
  const float* ln1_b = (const float*)d_in[9];
  const float* ln2_g = (const float*)d_in[10];
  const float* ln2_b = (const float*)d_in[11];
  const float* ff1_w = (const float*)d_in[12];
  const float* ff1_b = (const float*)d_in[13];
  const float* ff2_w = (const float*)d_in[14];
  const float* ff2_b = (const float*)d_in[15];
  const float* B_mat = (const float*)d_in[16];
  const float* dr1_w = (const float*)d_in[17];
  const float* dr1_b = (const float*)d_in[18];
  const float* dr2_w = (const float*)d_in[19];
  const float* dr2_b = (const float*)d_in[20];
  const float* tau1_w = (const float*)d_in[21];
  const float* tau1_b = (const float*)d_in[22];
  const float* tau2_w = (const float*)d_in[23];
  const float* tau2_b = (const float*)d_in[24];
  const float* fc_w = (const float*)d_in[25];
  const float* fc_b = (const float*)d_in[26];

  float* W = (float*)d_ws;
  float* A = W;              // 4096
  float* t1wp = W + 4096;    // 8192
  float* t1t = W + 12288;    // 128
  float* zcb = W + 12416;    // 4096*64

  prep_kernel<<<68, 64, 0, stream>>>(B_mat, tau1_w, A, t1wp, t1t);
  tf_kernel<<<4096, 256, 0, stream>>>(x, conv_w, conv_b, cls, attn_w, attn_b,
                                      out_w, out_b, ln1_g, ln1_b, ln2_g, ln2_b,
                                      ff1_w, ff1_b, ff2_w, ff2_b, zcb);
  ode_kernel<<<256, 512, 0, stream>>>(zcb, dr1_w, dr1_b, dr2_w, dr2_b,
                                      t1wp, t1t, tau1_b, tau2_w, tau2_b,
                                      A, fc_w, fc_b, (float*)d_out);
}

// Round 2
// 2162.022 us; speedup vs baseline: 3.3773x; 3.3773x over previous
//
#include <hip/hip_runtime.h>
#include <hip/hip_fp16.h>
#include <math.h>

#define DEV static __device__ __forceinline__

DEV float hsum4(const float4 v) { return (v.x + v.y) + (v.z + v.w); }
DEV float4 zero4() { return make_float4(0.f, 0.f, 0.f, 0.f); }
DEV void fma4(float4& a, const float4 x, const float4 w) {
  a.x = fmaf(x.x, w.x, a.x); a.y = fmaf(x.y, w.y, a.y);
  a.z = fmaf(x.z, w.z, a.z); a.w = fmaf(x.w, w.w, a.w);
}

// unpack 4 f16 (packed as uint2) -> float4
DEV float4 up4(const uint2 u) {
  const __half2 a = *(const __half2*)&u.x;
  const __half2 b = *(const __half2*)&u.y;
  float2 fa = __half22float2(a), fb = __half22float2(b);
  return make_float4(fa.x, fa.y, fb.x, fb.y);
}

DEV uint2 pk4(float a, float b, float c, float d) {
  uint2 r;
  r.x = (unsigned)__half_as_ushort(__float2half_rn(a)) |
        ((unsigned)__half_as_ushort(__float2half_rn(b)) << 16);
  r.y = (unsigned)__half_as_ushort(__float2half_rn(c)) |
        ((unsigned)__half_as_ushort(__float2half_rn(d)) << 16);
  return r;
}

// pair-row x col-quad register tile (tf_kernel helper, unchanged)
template <int KF4>
DEV void pair_tile(const float4* __restrict__ Xf, int xs4, int i0,
                   const float4* __restrict__ Wf, int ws4, int row0, int step,
                   float4* a0, float4* a1) {
#pragma unroll
  for (int q = 0; q < 4; ++q) { a0[q] = zero4(); a1[q] = zero4(); }
#pragma unroll
  for (int k4 = 0; k4 < KF4; ++k4) {
    float4 za = Xf[i0 * xs4 + k4];
    float4 zb = Xf[(i0 + 17) * xs4 + k4];
#pragma unroll
    for (int q = 0; q < 4; ++q) {
      float4 w = Wf[(row0 + step * q) * ws4 + k4];
      fma4(a0[q], za, w);
      fma4(a1[q], zb, w);
    }
  }
}

// ---------------- prep: pack ODE weights (f16, XOR-swizzled granules) ----------------
// ws stage blob layout (bytes):
//  0      dr1s  uint2[128*16]   (dr1_w [128][64])
//  16384  tau1s uint2[128*16]   (tau1_w [128][65], k<64)
//  32768  dr2s  uint2[64*32]    (dr2_w [64][128])
//  49152  tau2s uint2[64*32]    (tau2_w [64][128])
//  65536  As    uint2[64*16]    (A = -B^T B, [64][64])
//  73728  fb    float[512]      (dr1_b|tau1_b|dr2_b|tau2_b|t1t)
//  75776  zc    float[4096*64]
__global__ __launch_bounds__(64) void prep_kernel(
    const float* __restrict__ Bm,
    const float* __restrict__ dr1_w, const float* __restrict__ dr1_b,
    const float* __restrict__ dr2_w, const float* __restrict__ dr2_b,
    const float* __restrict__ tau1_w, const float* __restrict__ tau1_b,
    const float* __restrict__ tau2_w, const float* __restrict__ tau2_b,
    char* __restrict__ wsb) {
  uint2* dr1s = (uint2*)(wsb);
  uint2* tau1s = (uint2*)(wsb + 16384);
  uint2* dr2s = (uint2*)(wsb + 32768);
  uint2* tau2s = (uint2*)(wsb + 49152);
  uint2* As = (uint2*)(wsb + 65536);
  float* fb = (float*)(wsb + 73728);

  const int t = threadIdx.x, blk = blockIdx.x;
  if (blk < 16) {
    // A granules: 64 rows x 16 granules; 4 rows per block
    int row = blk * 4 + (t >> 4), g = t & 15;
    float a0 = 0.f, a1 = 0.f, a2 = 0.f, a3 = 0.f;
    for (int m = 0; m < 64; ++m) {
      float br = Bm[m * 64 + row];
      a0 = fmaf(br, Bm[m * 64 + 4 * g + 0], a0);
      a1 = fmaf(br, Bm[m * 64 + 4 * g + 1], a1);
      a2 = fmaf(br, Bm[m * 64 + 4 * g + 2], a2);
      a3 = fmaf(br, Bm[m * 64 + 4 * g + 3], a3);
    }
    As[row * 16 + (g ^ (row & 15))] = pk4(-a0, -a1, -a2, -a3);
  } else if (blk < 48) {
    int idx = (blk - 16) * 64 + t;  // 0..2047
    int row = idx >> 4, g = idx & 15;
    int d = row * 16 + (g ^ (row & 15));
    const float* w1 = dr1_w + row * 64 + 4 * g;
    dr1s[d] = pk4(w1[0], w1[1], w1[2], w1[3]);
    const float* w2 = tau1_w + row * 65 + 4 * g;
    tau1s[d] = pk4(w2[0], w2[1], w2[2], w2[3]);
  } else if (blk < 80) {
    int idx = (blk - 48) * 64 + t;  // 0..2047
    int row = idx >> 5, g = idx & 31;
    int d = row * 32 + (g ^ (row & 15));
    const float* w1 = dr2_w + row * 128 + 4 * g;
    dr2s[d] = pk4(w1[0], w1[1], w1[2], w1[3]);
    const float* w2 = tau2_w + row * 128 + 4 * g;
    tau2s[d] = pk4(w2[0], w2[1], w2[2], w2[3]);
  } else {
    int i = (blk - 80) * 64 + t;  // 0..511
    float v;
    if (i < 128) v = dr1_b[i];
    else if (i < 256) v = tau1_b[i - 128];
    else if (i < 320) v = dr2_b[i - 256];
    else if (i < 384) v = tau2_b[i - 320];
    else v = tau1_w[(i - 384) * 65 + 64];  // t-column
    fb[i] = v;
  }
}

// ---------------- transformer: unchanged from round 1 (passed) ----------------
__global__ __launch_bounds__(256) void tf_kernel(
    const float* __restrict__ x,
    const float* __restrict__ conv_w, const float* __restrict__ conv_b,
    const float* __restrict__ cls,
    const float* __restrict__ attn_w, const float* __restrict__ attn_b,
    const float* __restrict__ out_w, const float* __restrict__ out_b,
    const float* __restrict__ ln1_g, const float* __restrict__ ln1_b,
    const float* __restrict__ ln2_g, const float* __restrict__ ln2_b,
    const float* __restrict__ ff1_w, const float* __restrict__ ff1_b,
    const float* __restrict__ ff2_w, const float* __restrict__ ff2_b,
    float* __restrict__ zc) {
  __shared__ float L[15712];
  float* Z = L;
  float* QKV = L + 2312;
  float* R3 = L + 8976;
  float* R4 = L + 13332;
  float* lnm = L + 15644;
  float* lnr = L + 15678;
  float4* Zf = (float4*)Z;
  float4* QKVf = (float4*)QKV;
  float4* R3f = (float4*)R3;
  float4* R4f = (float4*)R4;

  const int t = threadIdx.x;
  const int b = blockIdx.x;

  float* CW = QKV;
  for (int idx = t; idx < 8192; idx += 256) {
    int d = idx >> 7, r = idx & 127;
    CW[d * 128 + (r & 15) * 8 + (r >> 4)] = conv_w[idx];
  }
  __syncthreads();

  {
    const int n = t & 31, dg = t >> 5;
    const float4* xg = (const float4*)(x + (size_t)b * 4096);
    const float4* cw4 = (const float4*)CW;
    float4 acc[8];
#pragma unroll
    for (int dd = 0; dd < 8; ++dd) acc[dd] = zero4();
    for (int p = 0; p < 16; ++p) {
      float4 xa = xg[(n * 16 + p) * 2 + 0];
      float4 xb = xg[(n * 16 + p) * 2 + 1];
#pragma unroll
      for (int dd = 0; dd < 8; ++dd) {
        int base = (dg * 8 + dd) * 32 + p * 2;
        fma4(acc[dd], xa, cw4[base]);
        fma4(acc[dd], xb, cw4[base + 1]);
      }
    }
#pragma unroll
    for (int dd = 0; dd < 8; ++dd) {
      int d = dg * 8 + dd;
      float v = hsum4(acc[dd]) + conv_b[d];
      float freq = expf(-0.14391157f * (float)(d & ~1));
      float ang = (float)(n + 1) * freq;
      v += (d & 1) ? cosf(ang) : sinf(ang);
      Z[(n + 1) * 68 + d] = v;
    }
  }
  if (t < 64) Z[t] = cls[t] + ((t & 1) ? 1.0f : 0.0f);
  if (t >= 64 && t < 132) Z[33 * 68 + (t - 64)] = 0.0f;
  __syncthreads();

  for (int l = 0; l < 3; ++l) {
    const float* AW = attn_w + l * 12288;
    const float* AB = attn_b + l * 192;

    for (int c = 0; c < 3; ++c) {
      const float4* awf = (const float4*)(AW + c * 4096);
      for (int i4 = t; i4 < 1024; i4 += 256)
        R3f[(i4 >> 4) * 17 + (i4 & 15)] = awf[i4];
      __syncthreads();
      for (int tile = t; tile < 272; tile += 256) {
        int i0 = tile >> 4, j4 = tile & 15;
        float4 a0[4], a1[4];
        pair_tile<16>(Zf, 17, i0, R3f, 17, j4, 16, a0, a1);
#pragma unroll
        for (int q = 0; q < 4; ++q) {
          int j = c * 64 + j4 + 16 * q;
          float bias = AB[j];
          QKV[i0 * 196 + j] = hsum4(a0[q]) + bias;
          QKV[(i0 + 17) * 196 + j] = hsum4(a1[q]) + bias;
        }
      }
      __syncthreads();
    }

    for (int idx = t; idx < 4356; idx += 256) {
      int r = idx / 33, kk = idx - r * 33;
      int h = r / 33, i = r - h * 33;
      float4 acc = zero4();
#pragma unroll
      for (int dq = 0; dq < 4; ++dq)
        fma4(acc, QKVf[i * 49 + h * 4 + dq], QKVf[kk * 49 + 16 + h * 4 + dq]);
      R3[r * 33 + kk] = 0.25f * hsum4(acc);
    }
    __syncthreads();

    if (t < 132) {
      float* s = R3 + t * 33;
      float mx = s[0];
      for (int kk = 1; kk < 33; ++kk) mx = fmaxf(mx, s[kk]);
      float sum = 0.f;
      for (int kk = 0; kk < 33; ++kk) { float e = expf(s[kk] - mx); s[kk] = e; sum += e; }
      float inv = 1.f / sum;
      for (int kk = 0; kk < 33; ++kk) s[kk] *= inv;
    }
    __syncthreads();

    for (int idx = t; idx < 528; idx += 256) {
      int i = idx >> 4, d4 = idx & 15, h = d4 >> 2;
      const float* srow = R3 + (h * 33 + i) * 33;
      float4 acc = zero4();
      for (int kk = 0; kk < 33; ++kk) {
        float a = srow[kk];
        float4 v4 = QKVf[kk * 49 + 32 + d4];
        acc.x = fmaf(a, v4.x, acc.x); acc.y = fmaf(a, v4.y, acc.y);
        acc.z = fmaf(a, v4.z, acc.z); acc.w = fmaf(a, v4.w, acc.w);
      }
      R4f[i * 17 + d4] = acc;
    }
    if (t < 17) R4f[33 * 17 + t] = zero4();
    __syncthreads();

    {
      const float4* owf = (const float4*)(out_w + l * 4096);
      for (int i4 = t; i4 < 1024; i4 += 256)
        R3f[(i4 >> 4) * 17 + (i4 & 15)] = owf[i4];
    }
    __syncthreads();

    for (int tile = t; tile < 272; tile += 256) {
      int i0 = tile >> 4, d4 = tile & 15;
      float4 a0[4], a1[4];
      pair_tile<16>(R4f, 17, i0, R3f, 17, d4, 16, a0, a1);
#pragma unroll
      for (int q = 0; q < 4; ++q) {
        int d = d4 + 16 * q;
        float bias = out_b[l * 64 + d];
        Z[i0 * 68 + d] += hsum4(a0[q]) + bias;
        Z[(i0 + 17) * 68 + d] += hsum4(a1[q]) + bias;
      }
    }
    __syncthreads();

    if (t < 33) {
      const float4* zr = (const float4*)(Z + t * 68);
      float4 s4 = zero4(), q4 = zero4();
      for (int k4 = 0; k4 < 16; ++k4) {
        float4 v = zr[k4];
        s4.x += v.x; s4.y += v.y; s4.z += v.z; s4.w += v.w;
        q4.x = fmaf(v.x, v.x, q4.x); q4.y = fmaf(v.y, v.y, q4.y);
        q4.z = fmaf(v.z, v.z, q4.z); q4.w = fmaf(v.w, v.w, q4.w);
      }
      float m = hsum4(s4) * 0.015625f;
      float var = hsum4(q4) * 0.015625f - m * m;
      lnm[t] = m; lnr[t] = rsqrtf(var + 1e-5f);
    }
    __syncthreads();
    for (int idx = t; idx < 2112; idx += 256) {
      int i = idx >> 6, d = idx & 63;
      Z[i * 68 + d] = (Z[i * 68 + d] - lnm[i]) * lnr[i] * ln1_g[l * 64 + d] + ln1_b[l * 64 + d];
    }
    __syncthreads();

    {
      const float4* wf = (const float4*)(ff1_w + l * 6144);
      for (int i4 = t; i4 < 1536; i4 += 256)
        QKVf[(i4 >> 4) * 17 + (i4 & 15)] = wf[i4];
    }
    __syncthreads();

    for (int tile = t; tile < 408; tile += 256) {
      int i0 = tile / 24, j4 = tile - i0 * 24;
      float4 a0[4], a1[4];
      pair_tile<16>(Zf, 17, i0, QKVf, 17, j4, 24, a0, a1);
#pragma unroll
      for (int q = 0; q < 4; ++q) {
        int j = j4 + 24 * q;
        float bias = ff1_b[l * 96 + j];
        R3[i0 * 100 + j] = fmaxf(hsum4(a0[q]) + bias, 0.f);
        R3[(i0 + 17) * 100 + j] = fmaxf(hsum4(a1[q]) + bias, 0.f);
      }
    }
    __syncthreads();

    {
      const float4* wf = (const float4*)(ff2_w + l * 6144);
      for (int i4 = t; i4 < 1536; i4 += 256) {
        int row = i4 / 24, k4 = i4 - row * 24;
        QKVf[row * 25 + k4] = wf[i4];
      }
    }
    __syncthreads();

    for (int tile = t; tile < 272; tile += 256) {
      int i0 = tile >> 4, d4 = tile & 15;
      float4 a0[4], a1[4];
      pair_tile<24>(R3f, 25, i0, QKVf, 25, d4, 16, a0, a1);
#pragma unroll
      for (int q = 0; q < 4; ++q) {
        int d = d4 + 16 * q;
        float bias = ff2_b[l * 64 + d];
        Z[i0 * 68 + d] += hsum4(a0[q]) + bias;
        Z[(i0 + 17) * 68 + d] += hsum4(a1[q]) + bias;
      }
    }
    __syncthreads();

    if (t < 33) {
      const float4* zr = (const float4*)(Z + t * 68);
      float4 s4 = zero4(), q4 = zero4();
      for (int k4 = 0; k4 < 16; ++k4) {
        float4 v = zr[k4];
        s4.x += v.x; s4.y += v.y; s4.z += v.z; s4.w += v.w;
        q4.x = fmaf(v.x, v.x, q4.x); q4.y = fmaf(v.y, v.y, q4.y);
        q4.z = fmaf(v.z, v.z, q4.z); q4.w = fmaf(v.w, v.w, q4.w);
      }
      float m = hsum4(s4) * 0.015625f;
      float var = hsum4(q4) * 0.015625f - m * m;
      lnm[t] = m; lnr[t] = rsqrtf(var + 1e-5f);
    }
    __syncthreads();
    for (int idx = t; idx < 2112; idx += 256) {
      int i = idx >> 6, d = idx & 63;
      Z[i * 68 + d] = (Z[i * 68 + d] - lnm[i]) * lnr[i] * ln2_g[l * 64 + d] + ln2_b[l * 64 + d];
    }
    __syncthreads();
  }

  if (t < 64) zc[(size_t)b * 64 + t] = Z[t];
}

// ---------------- ODE: 32 Euler steps, all weights resident in LDS (f16) ----------------
// LDS layout (bytes):
//  0      dr1s  16384 | 16384 tau1s | 32768 dr2s 16384 | 49152 tau2s 16384
//  65536  As 8192 | 73728 fb 2048 | 75776 ZT f32 16x68 | 80128 HID f32 16x132
//  88576  DRV | 92928 TAU | 97280 ZA  (each f32 16x68)  -> total 101632
__global__ __launch_bounds__(512) void ode_kernel(
    const char* __restrict__ stg, const float* __restrict__ zc,
    const float* __restrict__ fc_w, const float* __restrict__ fc_b,
    float* __restrict__ out) {
  __shared__ __align__(16) unsigned char SH[101632];
  const uint2* dr1s = (const uint2*)(SH);
  const uint2* tau1s = (const uint2*)(SH + 16384);
  const uint2* dr2s = (const uint2*)(SH + 32768);
  const uint2* tau2s = (const uint2*)(SH + 49152);
  const uint2* As = (const uint2*)(SH + 65536);
  const float* fb = (const float*)(SH + 73728);
  float* ZT = (float*)(SH + 75776);
  float* HID = (float*)(SH + 80128);
  float* DRV = (float*)(SH + 88576);
  float* TAU = (float*)(SH + 92928);
  float* ZA = (float*)(SH + 97280);
  float4* ZTf = (float4*)ZT;
  float4* HIDf = (float4*)HID;

  const int t = threadIdx.x;
  const int b0 = blockIdx.x * 16;

  // stage weights global->LDS (75776 B = 4736 uint4)
  {
    const uint4* src = (const uint4*)stg;
    uint4* dst = (uint4*)SH;
    for (int i = t; i < 4736; i += 512) dst[i] = src[i];
  }
  if (t < 256) ZTf[(t >> 4) * 17 + (t & 15)] = ((const float4*)(zc + (size_t)b0 * 64))[t];
  __syncthreads();

  const int bb = t >> 5;   // batch row 0..15
  const int j4 = t & 31;   // col group 0..31
  const int xmask = j4 & 15;
  float tm = 0.f;

  for (int s = 0; s < 32; ++s) {
    // ---- hid_drive = tanh(zt @ dr1^T + b): cols {j4 + 32q} ----
    {
      float4 a0 = zero4(), a1 = zero4(), a2 = zero4(), a3 = zero4();
#pragma unroll
      for (int k4 = 0; k4 < 16; ++k4) {
        float4 z4 = ZTf[bb * 17 + k4];
        int g = k4 ^ xmask;
        fma4(a0, z4, up4(dr1s[(j4) * 16 + g]));
        fma4(a1, z4, up4(dr1s[(j4 + 32) * 16 + g]));
        fma4(a2, z4, up4(dr1s[(j4 + 64) * 16 + g]));
        fma4(a3, z4, up4(dr1s[(j4 + 96) * 16 + g]));
      }
      HID[bb * 132 + j4] = tanhf(hsum4(a0) + fb[j4]);
      HID[bb * 132 + j4 + 32] = tanhf(hsum4(a1) + fb[j4 + 32]);
      HID[bb * 132 + j4 + 64] = tanhf(hsum4(a2) + fb[j4 + 64]);
      HID[bb * 132 + j4 + 96] = tanhf(hsum4(a3) + fb[j4 + 96]);
    }
    __syncthreads();
    // ---- drive = hid @ dr2^T + b ; zA = zt @ A : cols {j4, j4+32} ----
    {
      float4 a0 = zero4(), a1 = zero4();
#pragma unroll
      for (int k4 = 0; k4 < 32; ++k4) {
        float4 h4 = HIDf[bb * 33 + k4];
        int g = k4 ^ xmask;
        fma4(a0, h4, up4(dr2s[(j4) * 32 + g]));
        fma4(a1, h4, up4(dr2s[(j4 + 32) * 32 + g]));
      }
      float4 g0 = zero4(), g1 = zero4();
#pragma unroll
      for (int k4 = 0; k4 < 16; ++k4) {
        float4 z4 = ZTf[bb * 17 + k4];
        int g = k4 ^ xmask;
        fma4(g0, z4, up4(As[(j4) * 16 + g]));
        fma4(g1, z4, up4(As[(j4 + 32) * 16 + g]));
      }
      DRV[bb * 68 + j4] = hsum4(a0) + fb[256 + j4];
      DRV[bb * 68 + j4 + 32] = hsum4(a1) + fb[256 + j4 + 32];
      ZA[bb * 68 + j4] = hsum4(g0);
      ZA[bb * 68 + j4 + 32] = hsum4(g1);
    }
    __syncthreads();
    // ---- hid_tau = tanh([zt,t] @ tau1^T + b) ----
    {
      float4 a0 = zero4(), a1 = zero4(), a2 = zero4(), a3 = zero4();
#pragma unroll
      for (int k4 = 0; k4 < 16; ++k4) {
        float4 z4 = ZTf[bb * 17 + k4];
        int g = k4 ^ xmask;
        fma4(a0, z4, up4(tau1s[(j4) * 16 + g]));
        fma4(a1, z4, up4(tau1s[(j4 + 32) * 16 + g]));
        fma4(a2, z4, up4(tau1s[(j4 + 64) * 16 + g]));
        fma4(a3, z4, up4(tau1s[(j4 + 96) * 16 + g]));
      }
      HID[bb * 132 + j4] = tanhf(hsum4(a0) + fmaf(tm, fb[384 + j4], fb[128 + j4]));
      HID[bb * 132 + j4 + 32] = tanhf(hsum4(a1) + fmaf(tm, fb[384 + j4 + 32], fb[128 + j4 + 32]));
      HID[bb * 132 + j4 + 64] = tanhf(hsum4(a2) + fmaf(tm, fb[384 + j4 + 64], fb[128 + j4 + 64]));
      HID[bb * 132 + j4 + 96] = tanhf(hsum4(a3) + fmaf(tm, fb[384 + j4 + 96], fb[128 + j4 + 96]));
    }
    __syncthreads();
    // ---- tau_raw = hid @ tau2^T + b ----
    {
      float4 a0 = zero4(), a1 = zero4();
#pragma unroll
      for (int k4 = 0; k4 < 32; ++k4) {
        float4 h4 = HIDf[bb * 33 + k4];
        int g = k4 ^ xmask;
        fma4(a0, h4, up4(tau2s[(j4) * 32 + g]));
        fma4(a1, h4, up4(tau2s[(j4 + 32) * 32 + g]));
      }
      TAU[bb * 68 + j4] = hsum4(a0) + fb[320 + j4];
      TAU[bb * 68 + j4 + 32] = hsum4(a1) + fb[320 + j4 + 32];
    }
    __syncthreads();
    // ---- combine: zt += h * (zA + inv*(drive - zt)) ----
    for (int idx = t; idx < 1024; idx += 512) {
      int bi = idx >> 6, d = idx & 63;
      float ztv = ZT[bi * 68 + d];
      float traw = TAU[bi * 68 + d];
      float sp = (traw > 15.f) ? traw : log1pf(expf(traw));
      float sg = 1.f / (1.f + expf(-(sp + 1e-6f)));
      float tau = fmaf(4.95f, sg, 0.05f);
      float inv = 1.f / tau;
      float dz = ZA[bi * 68 + d] + inv * (DRV[bi * 68 + d] - ztv);
      ZT[bi * 68 + d] = fmaf(0.03125f, dz, ztv);
    }
    __syncthreads();
    tm += 0.03125f;
  }

  // final FC: out[b][192]
  for (int idx = t; idx < 768; idx += 512) {
    int bi = idx / 48, qd = idx - bi * 48;
    const float4* w = (const float4*)fc_w;
    float4 a0 = zero4(), a1 = zero4(), a2 = zero4(), a3 = zero4();
    for (int k4 = 0; k4 < 16; ++k4) {
      float4 z4 = ZTf[bi * 17 + k4];
      fma4(a0, z4, w[(qd * 4 + 0) * 16 + k4]);
      fma4(a1, z4, w[(qd * 4 + 1) * 16 + k4]);
      fma4(a2, z4, w[(qd * 4 + 2) * 16 + k4]);
      fma4(a3, z4, w[(qd * 4 + 3) * 16 + k4]);
    }
    float4 r;
    r.x = hsum4(a0) + fc_b[qd * 4 + 0];
    r.y = hsum4(a1) + fc_b[qd * 4 + 1];
    r.z = hsum4(a2) + fc_b[qd * 4 + 2];
    r.w = hsum4(a3) + fc_b[qd * 4 + 3];
    ((float4*)(out + (size_t)(b0 + bi) * 192))[qd] = r;
  }
}

extern "C" void kernel_launch(void* const* d_in, const int* in_sizes, int n_in,
                              void* d_out, int out_size, void* d_ws, size_t ws_size,
                              hipStream_t stream) {
  const float* x = (const float*)d_in[0];
  const float* conv_w = (const float*)d_in[1];
  const float* conv_b = (const float*)d_in[2];
  const float* cls = (const float*)d_in[3];
  const float* attn_w = (const float*)d_in[4];
  const float* attn_b = (const float*)d_in[5];
  const float* out_w = (const float*)d_in[6];
  const float* out_b = (const float*)d_in[7];
  const float* ln1_g = (const float*)d_in[8];
  const float* ln1_b = (const float*)d_in[9];
  const float* ln2_g = (const float*)d_in[10];
  const float* ln2_b = (const float*)d_in[11];
  const float* ff1_w = (const float*)d_in[12];
  const float* ff1_b = (const float*)d_in[13];
  const float* ff2_w = (const float*)d_in[14];
  const float* ff2_b = (const float*)d_in[15];
  const float* B_mat = (const float*)d_in[16];
  const float* dr1_w = (const float*)d_in[17];
  const float* dr1_b = (const float*)d_in[18];
  const float* dr2_w = (const float*)d_in[19];
  const float* dr2_b = (const float*)d_in[20];
  const float* tau1_w = (const float*)d_in[21];
  const float* tau1_b = (const float*)d_in[22];
  const float* tau2_w = (const float*)d_in[23];
  const float* tau2_b = (const float*)d_in[24];
  const float* fc_w = (const float*)d_in[25];
  const float* fc_b = (const float*)d_in[26];

  char* wsb = (char*)d_ws;
  float* zcb = (float*)(wsb + 75776);

  prep_kernel<<<88, 64, 0, stream>>>(B_mat, dr1_w, dr1_b, dr2_w, dr2_b,
                                     tau1_w, tau1_b, tau2_w, tau2_b, wsb);
  tf_kernel<<<4096, 256, 0, stream>>>(x, conv_w, conv_b, cls, attn_w, attn_b,
                                      out_w, out_b, ln1_g, ln1_b, ln2_g, ln2_b,
                                      ff1_w, ff1_b, ff2_w, ff2_b, zcb);
  ode_kernel<<<256, 512, 0, stream>>>(wsb, zcb, fc_w, fc_b, (float*)d_out);
}

// Round 3
// 1207.171 us; speedup vs baseline: 6.0487x; 1.7910x over previous
//
#include <hip/hip_runtime.h>
#include <hip/hip_fp16.h>
#include <math.h>

#define DEV static __device__ __forceinline__

typedef _Float16 f16;
typedef __attribute__((ext_vector_type(4))) _Float16 f16x4;
typedef __attribute__((ext_vector_type(8))) _Float16 f16x8;
typedef __attribute__((ext_vector_type(4))) float f32x4;

DEV float hsum4(const float4 v) { return (v.x + v.y) + (v.z + v.w); }
DEV float4 zero4() { return make_float4(0.f, 0.f, 0.f, 0.f); }
DEV void fma4(float4& a, const float4 x, const float4 w) {
  a.x = fmaf(x.x, w.x, a.x); a.y = fmaf(x.y, w.y, a.y);
  a.z = fmaf(x.z, w.z, a.z); a.w = fmaf(x.w, w.w, a.w);
}
DEV float4 up4(const uint2 u) {
  const __half2 a = *(const __half2*)&u.x;
  const __half2 b = *(const __half2*)&u.y;
  float2 fa = __half22float2(a), fb = __half22float2(b);
  return make_float4(fa.x, fa.y, fb.x, fb.y);
}
DEV uint2 pk4(float a, float b, float c, float d) {
  uint2 r;
  r.x = (unsigned)__half_as_ushort(__float2half_rn(a)) |
        ((unsigned)__half_as_ushort(__float2half_rn(b)) << 16);
  r.y = (unsigned)__half_as_ushort(__float2half_rn(c)) |
        ((unsigned)__half_as_ushort(__float2half_rn(d)) << 16);
  return r;
}

DEV f16x8 ld8(const f16* p) { return *(const f16x8*)p; }
DEV f32x4 mfma32(f16x8 a, f16x8 b, f32x4 c) {
  return __builtin_amdgcn_mfma_f32_16x16x32_f16(a, b, c, 0, 0, 0);
}

// ---------------- prep: ODE weights (f16, XOR-swizzled granules) ----------------
// ws blob: 0 dr1s | 16384 tau1s | 32768 dr2s | 49152 tau2s | 65536 As | 73728 fb
__global__ __launch_bounds__(64) void prep_kernel(
    const float* __restrict__ Bm,
    const float* __restrict__ dr1_w, const float* __restrict__ dr1_b,
    const float* __restrict__ dr2_w, const float* __restrict__ dr2_b,
    const float* __restrict__ tau1_w, const float* __restrict__ tau1_b,
    const float* __restrict__ tau2_w, const float* __restrict__ tau2_b,
    char* __restrict__ wsb) {
  uint2* dr1s = (uint2*)(wsb);
  uint2* tau1s = (uint2*)(wsb + 16384);
  uint2* dr2s = (uint2*)(wsb + 32768);
  uint2* tau2s = (uint2*)(wsb + 49152);
  uint2* As = (uint2*)(wsb + 65536);
  float* fb = (float*)(wsb + 73728);

  const int t = threadIdx.x, blk = blockIdx.x;
  if (blk < 16) {
    int row = blk * 4 + (t >> 4), g = t & 15;
    float a0 = 0.f, a1 = 0.f, a2 = 0.f, a3 = 0.f;
    for (int m = 0; m < 64; ++m) {
      float br = Bm[m * 64 + row];
      a0 = fmaf(br, Bm[m * 64 + 4 * g + 0], a0);
      a1 = fmaf(br, Bm[m * 64 + 4 * g + 1], a1);
      a2 = fmaf(br, Bm[m * 64 + 4 * g + 2], a2);
      a3 = fmaf(br, Bm[m * 64 + 4 * g + 3], a3);
    }
    As[row * 16 + (g ^ (row & 15))] = pk4(-a0, -a1, -a2, -a3);
  } else if (blk < 48) {
    int idx = (blk - 16) * 64 + t;
    int row = idx >> 4, g = idx & 15;
    int d = row * 16 + (g ^ (row & 15));
    const float* w1 = dr1_w + row * 64 + 4 * g;
    dr1s[d] = pk4(w1[0], w1[1], w1[2], w1[3]);
    const float* w2 = tau1_w + row * 65 + 4 * g;
    tau1s[d] = pk4(w2[0], w2[1], w2[2], w2[3]);
  } else if (blk < 80) {
    int idx = (blk - 48) * 64 + t;
    int row = idx >> 5, g = idx & 31;
    int d = row * 32 + (g ^ (row & 15));
    const float* w1 = dr2_w + row * 128 + 4 * g;
    dr2s[d] = pk4(w1[0], w1[1], w1[2], w1[3]);
    const float* w2 = tau2_w + row * 128 + 4 * g;
    tau2s[d] = pk4(w2[0], w2[1], w2[2], w2[3]);
  } else {
    int i = (blk - 80) * 64 + t;
    float v;
    if (i < 128) v = dr1_b[i];
    else if (i < 256) v = tau1_b[i - 128];
    else if (i < 320) v = dr2_b[i - 256];
    else if (i < 384) v = tau2_b[i - 320];
    else v = tau1_w[(i - 384) * 65 + 64];
    fb[i] = v;
  }
}

// ---------------- prep_tf: convert tf weights to f16, padded LDS-exact layouts ----
// tfw (f16 units): 0 CW [64][136] (8704) ; layer l at 8704+l*32000:
//   +0 qkvW 3x[64][72] | +13824 outW [64][72] | +18432 ff1W [96][72] | +25344 ff2W [64][104]
__global__ __launch_bounds__(256) void prep_tf(
    const float* __restrict__ conv_w, const float* __restrict__ attn_w,
    const float* __restrict__ out_w, const float* __restrict__ ff1_w,
    const float* __restrict__ ff2_w, f16* __restrict__ tfw) {
  int idx = blockIdx.x * 256 + threadIdx.x;
  if (idx < 8704) {
    int d = idx / 136, k = idx - d * 136;
    float v = (k < 128) ? conv_w[d * 128 + (k & 7) * 16 + (k >> 3)] : 0.f;
    tfw[idx] = (f16)v;
    return;
  }
  idx -= 8704;
  int l = idx / 32000;
  if (l >= 3) return;
  int r = idx - l * 32000;
  f16* ld = tfw + 8704 + l * 32000;
  float v;
  if (r < 13824) {
    int c = r / 4608, rr = r - c * 4608, j = rr / 72, k = rr - j * 72;
    v = (k < 64) ? attn_w[l * 12288 + (c * 64 + j) * 64 + k] : 0.f;
  } else if (r < 18432) {
    int rr = r - 13824, j = rr / 72, k = rr - j * 72;
    v = (k < 64) ? out_w[l * 4096 + j * 64 + k] : 0.f;
  } else if (r < 25344) {
    int rr = r - 18432, j = rr / 72, k = rr - j * 72;
    v = (k < 64) ? ff1_w[l * 6144 + j * 64 + k] : 0.f;
  } else {
    int rr = r - 25344, j = rr / 104, k = rr - j * 104;
    v = (k < 96) ? ff2_w[l * 6144 + j * 96 + k] : 0.f;
  }
  ld[r] = (f16)v;
}

// ---------------- transformer: MFMA, 1 block per batch, 4 waves ----------------
// LDS: Zm f32[48][68] | Zh f16[48][72] | Qh | Kh | VT f16[64][72] | oh |
//      Wh 17408 (CW[64][136]/qkvW/outW/ff1W[96][72]/ff2W[64][104]; P f16[4][48][40] alias)
//      Sx 9984 (xh f16[32][136] / f1h f16[48][104]) | lnm/lnr f32[48]
__global__ __launch_bounds__(256, 2) void tf_kernel(
    const float* __restrict__ x, const f16* __restrict__ tfw,
    const float* __restrict__ conv_b, const float* __restrict__ cls,
    const float* __restrict__ attn_b, const float* __restrict__ out_b,
    const float* __restrict__ ln1_g, const float* __restrict__ ln1_b,
    const float* __restrict__ ln2_g, const float* __restrict__ ln2_b,
    const float* __restrict__ ff1_b, const float* __restrict__ ff2_b,
    float* __restrict__ zc) {
  __shared__ __align__(16) unsigned char SH[77696];
  float* Zm = (float*)SH;
  f16* Zh = (f16*)(SH + 13056);
  f16* Qh = (f16*)(SH + 19968);
  f16* Kh = (f16*)(SH + 26880);
  f16* VT = (f16*)(SH + 33792);
  f16* oh = (f16*)(SH + 43008);
  f16* Wh = (f16*)(SH + 49920);
  f16* Sx = (f16*)(SH + 67328);
  float* lnm = (float*)(SH + 77312);
  float* lnr = (float*)(SH + 77504);

  const int t = threadIdx.x;
  const int b = blockIdx.x;
  const int w = t >> 6, lane = t & 63;
  const int c16 = lane & 15, q4 = lane >> 4;

  // ---- stage: CW, xh(f16), cls row, zero pads ----
  {
    const uint4* src = (const uint4*)tfw;
    uint4* dst = (uint4*)Wh;
    for (int i = t; i < 1088; i += 256) dst[i] = src[i];
    const float4* xg = (const float4*)(x + (size_t)b * 4096);
    for (int i = t; i < 1024; i += 256) {
      int n = i >> 5, j = i & 31;
      float4 v = xg[n * 32 + j];
      f16x4 h4 = {(f16)v.x, (f16)v.y, (f16)v.z, (f16)v.w};
      *(f16x4*)(Sx + n * 136 + j * 4) = h4;
    }
    for (int i = t; i < 1020; i += 256) Zm[33 * 68 + i] = 0.f;
    unsigned* zp = (unsigned*)(Zh + 33 * 72);
    for (int i = t; i < 540; i += 256) zp[i] = 0u;
    unsigned* vp = (unsigned*)VT;
    for (int i = t; i < 2304; i += 256) vp[i] = 0u;
    if (t < 64) {
      float v = cls[t] + ((t & 1) ? 1.0f : 0.0f);
      Zm[t] = v; Zh[t] = (f16)v;
    }
  }
  __syncthreads();

  // ---- patch embed (MFMA) + pos enc ----
  {
    f16x8 bw[4];
#pragma unroll
    for (int kb = 0; kb < 4; ++kb)
      bw[kb] = ld8(Wh + (w * 16 + c16) * 136 + kb * 32 + q4 * 8);
    int d = w * 16 + c16;
    float cb = conv_b[d];
    float freq = __expf(-0.14391157f * (float)(d & ~1));
#pragma unroll
    for (int rt = 0; rt < 2; ++rt) {
      f32x4 acc = {};
#pragma unroll
      for (int kb = 0; kb < 4; ++kb)
        acc = mfma32(ld8(Sx + (rt * 16 + c16) * 136 + kb * 32 + q4 * 8), bw[kb], acc);
#pragma unroll
      for (int r = 0; r < 4; ++r) {
        int zr = rt * 16 + q4 * 4 + r + 1;
        float ang = (float)zr * freq;
        float pe = (d & 1) ? cosf(ang) : sinf(ang);
        float val = acc[r] + cb + pe;
        Zm[zr * 68 + d] = val;
        Zh[zr * 72 + d] = (f16)val;
      }
    }
  }
  __syncthreads();

  for (int l = 0; l < 3; ++l) {
    const f16* lw = tfw + 8704 + l * 32000;

    // ---- qkv: 3 chunks of 64 cols ----
    for (int c = 0; c < 3; ++c) {
      {
        const uint4* src = (const uint4*)(lw + c * 4608);
        uint4* dst = (uint4*)Wh;
        for (int i = t; i < 576; i += 256) dst[i] = src[i];
      }
      __syncthreads();
      {
        int j = w * 16 + c16;
        float bias = attn_b[l * 192 + c * 64 + j];
        f16x8 b0 = ld8(Wh + j * 72 + q4 * 8);
        f16x8 b1 = ld8(Wh + j * 72 + 32 + q4 * 8);
#pragma unroll
        for (int rt = 0; rt < 3; ++rt) {
          f32x4 acc = {};
          acc = mfma32(ld8(Zh + (rt * 16 + c16) * 72 + q4 * 8), b0, acc);
          acc = mfma32(ld8(Zh + (rt * 16 + c16) * 72 + 32 + q4 * 8), b1, acc);
          if (c == 0) {
#pragma unroll
            for (int r = 0; r < 4; ++r)
              Qh[(rt * 16 + q4 * 4 + r) * 72 + j] = (f16)((acc[r] + bias) * 0.25f);
          } else if (c == 1) {
#pragma unroll
            for (int r = 0; r < 4; ++r)
              Kh[(rt * 16 + q4 * 4 + r) * 72 + j] = (f16)(acc[r] + bias);
          } else {
            if (rt < 2) {
              f16x4 pv = {(f16)(acc[0] + bias), (f16)(acc[1] + bias),
                          (f16)(acc[2] + bias), (f16)(acc[3] + bias)};
              *(f16x4*)(VT + j * 72 + rt * 16 + q4 * 4) = pv;
            } else if (q4 == 0) {
              VT[j * 72 + 32] = (f16)(acc[0] + bias);
            }
          }
        }
      }
      __syncthreads();
    }

    // ---- scores (per-wave head, regs; K=16 zero-padded to 32) + zero P ----
    f32x4 s[3][3];
    {
      f16x8 zf = {};
      f16x8 aq[3], bk[3];
#pragma unroll
      for (int rt = 0; rt < 3; ++rt)
        aq[rt] = (q4 < 2) ? ld8(Qh + (rt * 16 + c16) * 72 + w * 16 + q4 * 8) : zf;
#pragma unroll
      for (int ck = 0; ck < 3; ++ck)
        bk[ck] = (q4 < 2) ? ld8(Kh + (ck * 16 + c16) * 72 + w * 16 + q4 * 8) : zf;
#pragma unroll
      for (int rt = 0; rt < 3; ++rt)
#pragma unroll
        for (int ck = 0; ck < 3; ++ck) {
          f32x4 zz = {};
          s[rt][ck] = mfma32(aq[rt], bk[ck], zz);
        }
      unsigned* pp = (unsigned*)Wh;  // P: [4][48][40] f16 = 15360 B
      for (int i = t; i < 3840; i += 256) pp[i] = 0u;
    }
    __syncthreads();

    // ---- in-register softmax (rows via shuffle over 16 lanes) + write P ----
    {
      f16* Ph = Wh + w * 1920;
#pragma unroll
      for (int rt = 0; rt < 3; ++rt) {
#pragma unroll
        for (int r = 0; r < 4; ++r) {
          float v0 = s[rt][0][r], v1 = s[rt][1][r];
          float v2 = (c16 == 0) ? s[rt][2][r] : -1e30f;  // only kk=32 valid in tile 2
          float m = fmaxf(fmaxf(v0, v1), v2);
          m = fmaxf(m, __shfl_xor(m, 1));
          m = fmaxf(m, __shfl_xor(m, 2));
          m = fmaxf(m, __shfl_xor(m, 4));
          m = fmaxf(m, __shfl_xor(m, 8));
          float e0 = __expf(v0 - m), e1 = __expf(v1 - m);
          float e2 = (c16 == 0) ? __expf(v2 - m) : 0.f;
          float su = e0 + e1 + e2;
          su += __shfl_xor(su, 1);
          su += __shfl_xor(su, 2);
          su += __shfl_xor(su, 4);
          su += __shfl_xor(su, 8);
          float inv = 1.f / su;
          int i = rt * 16 + q4 * 4 + r;
          if (i < 33) {
            Ph[i * 40 + c16] = (f16)(e0 * inv);
            Ph[i * 40 + 16 + c16] = (f16)(e1 * inv);
            if (c16 == 0) Ph[i * 40 + 32] = (f16)(e2 * inv);
          }
        }
      }
    }
    __syncthreads();

    // ---- PV (K=32 mfma + rank-1 for kk=32) ----
    {
      const f16* Ph = Wh + w * 1920;
      int d = w * 16 + c16;
      f16x8 bv = ld8(VT + d * 72 + q4 * 8);
      float v32 = (float)VT[d * 72 + 32];
#pragma unroll
      for (int rt = 0; rt < 3; ++rt) {
        f32x4 acc = {};
        acc = mfma32(ld8(Ph + (rt * 16 + c16) * 40 + q4 * 8), bv, acc);
#pragma unroll
        for (int r = 0; r < 4; ++r) {
          int i = rt * 16 + q4 * 4 + r;
          float o = acc[r] + (float)Ph[i * 40 + 32] * v32;
          oh[i * 72 + d] = (f16)o;
        }
      }
    }
    __syncthreads();

    // ---- stage outW ----
    {
      const uint4* src = (const uint4*)(lw + 13824);
      uint4* dst = (uint4*)Wh;
      for (int i = t; i < 576; i += 256) dst[i] = src[i];
    }
    __syncthreads();

    // ---- out-proj: Zm += oh @ outW^T + b ----
    {
      int d = w * 16 + c16;
      float bias = out_b[l * 64 + d];
      f16x8 b0 = ld8(Wh + d * 72 + q4 * 8);
      f16x8 b1 = ld8(Wh + d * 72 + 32 + q4 * 8);
#pragma unroll
      for (int rt = 0; rt < 3; ++rt) {
        f32x4 acc = {};
        acc = mfma32(ld8(oh + (rt * 16 + c16) * 72 + q4 * 8), b0, acc);
        acc = mfma32(ld8(oh + (rt * 16 + c16) * 72 + 32 + q4 * 8), b1, acc);
#pragma unroll
        for (int r = 0; r < 4; ++r) {
          int i = rt * 16 + q4 * 4 + r;
          if (i < 33) Zm[i * 68 + d] += acc[r] + bias;
        }
      }
    }
    __syncthreads();

    // ---- LN1 stats (33 rows x 4 lanes, shuffle reduce) ----
    if (t < 132) {
      int row = t >> 2, l4 = t & 3;
      const float4* zr = (const float4*)(Zm + row * 68 + l4 * 16);
      float su = 0.f, ss = 0.f;
#pragma unroll
      for (int c4 = 0; c4 < 4; ++c4) {
        float4 v = zr[c4];
        su += (v.x + v.y) + (v.z + v.w);
        ss = fmaf(v.x, v.x, ss); ss = fmaf(v.y, v.y, ss);
        ss = fmaf(v.z, v.z, ss); ss = fmaf(v.w, v.w, ss);
      }
      su += __shfl_xor(su, 1); su += __shfl_xor(su, 2);
      ss += __shfl_xor(ss, 1); ss += __shfl_xor(ss, 2);
      float m = su * 0.015625f;
      float var = ss * 0.015625f - m * m;
      if (l4 == 0) { lnm[row] = m; lnr[row] = rsqrtf(var + 1e-5f); }
    }
    __syncthreads();

    // ---- norm1 + Zh refresh + stage ff1W ----
    {
      const uint4* src = (const uint4*)(lw + 18432);
      uint4* dst = (uint4*)Wh;
      for (int i = t; i < 864; i += 256) dst[i] = src[i];
      for (int idx = t; idx < 2112; idx += 256) {
        int i = idx >> 6, d = idx & 63;
        float val = (Zm[i * 68 + d] - lnm[i]) * lnr[i] * ln1_g[l * 64 + d] + ln1_b[l * 64 + d];
        Zm[i * 68 + d] = val;
        Zh[i * 72 + d] = (f16)val;
      }
    }
    __syncthreads();

    // ---- ff1: f1h = relu(Zh @ ff1W^T + b) ----
    {
      f16* f1h = Sx;
      f16x8 a0[3], a1[3];
#pragma unroll
      for (int rt = 0; rt < 3; ++rt) {
        a0[rt] = ld8(Zh + (rt * 16 + c16) * 72 + q4 * 8);
        a1[rt] = ld8(Zh + (rt * 16 + c16) * 72 + 32 + q4 * 8);
      }
      for (int cc = w; cc < 6; cc += 4) {
        int j = cc * 16 + c16;
        float bias = ff1_b[l * 96 + j];
        f16x8 b0 = ld8(Wh + j * 72 + q4 * 8);
        f16x8 b1 = ld8(Wh + j * 72 + 32 + q4 * 8);
#pragma unroll
        for (int rt = 0; rt < 3; ++rt) {
          f32x4 acc = {};
          acc = mfma32(a0[rt], b0, acc);
          acc = mfma32(a1[rt], b1, acc);
#pragma unroll
          for (int r = 0; r < 4; ++r)
            f1h[(rt * 16 + q4 * 4 + r) * 104 + j] = (f16)fmaxf(acc[r] + bias, 0.f);
        }
      }
    }
    __syncthreads();

    // ---- stage ff2W ----
    {
      const uint4* src = (const uint4*)(lw + 25344);
      uint4* dst = (uint4*)Wh;
      for (int i = t; i < 832; i += 256) dst[i] = src[i];
    }
    __syncthreads();

    // ---- ff2: Zm += f1h @ ff2W^T + b ----
    {
      const f16* f1h = Sx;
      int d = w * 16 + c16;
      float bias = ff2_b[l * 64 + d];
      f16x8 b0 = ld8(Wh + d * 104 + q4 * 8);
      f16x8 b1 = ld8(Wh + d * 104 + 32 + q4 * 8);
      f16x8 b2 = ld8(Wh + d * 104 + 64 + q4 * 8);
#pragma unroll
      for (int rt = 0; rt < 3; ++rt) {
        f32x4 acc = {};
        acc = mfma32(ld8(f1h + (rt * 16 + c16) * 104 + q4 * 8), b0, acc);
        acc = mfma32(ld8(f1h + (rt * 16 + c16) * 104 + 32 + q4 * 8), b1, acc);
        acc = mfma32(ld8(f1h + (rt * 16 + c16) * 104 + 64 + q4 * 8), b2, acc);
#pragma unroll
        for (int r = 0; r < 4; ++r) {
          int i = rt * 16 + q4 * 4 + r;
          if (i < 33) Zm[i * 68 + d] += acc[r] + bias;
        }
      }
    }
    __syncthreads();

    // ---- LN2 stats ----
    if (t < 132) {
      int row = t >> 2, l4 = t & 3;
      const float4* zr = (const float4*)(Zm + row * 68 + l4 * 16);
      float su = 0.f, ss = 0.f;
#pragma unroll
      for (int c4 = 0; c4 < 4; ++c4) {
        float4 v = zr[c4];
        su += (v.x + v.y) + (v.z + v.w);
        ss = fmaf(v.x, v.x, ss); ss = fmaf(v.y, v.y, ss);
        ss = fmaf(v.z, v.z, ss); ss = fmaf(v.w, v.w, ss);
      }
      su += __shfl_xor(su, 1); su += __shfl_xor(su, 2);
      ss += __shfl_xor(ss, 1); ss += __shfl_xor(ss, 2);
      float m = su * 0.015625f;
      float var = ss * 0.015625f - m * m;
      if (l4 == 0) { lnm[row] = m; lnr[row] = rsqrtf(var + 1e-5f); }
    }
    __syncthreads();

    // ---- norm2 + Zh refresh (+ zc write on last layer) ----
    for (int idx = t; idx < 2112; idx += 256) {
      int i = idx >> 6, d = idx & 63;
      float val = (Zm[i * 68 + d] - lnm[i]) * lnr[i] * ln2_g[l * 64 + d] + ln2_b[l * 64 + d];
      Zm[i * 68 + d] = val;
      Zh[i * 72 + d] = (f16)val;
      if (l == 2 && i == 0) zc[(size_t)b * 64 + d] = val;
    }
    __syncthreads();
  }
}

// ---------------- ODE: 32 Euler steps, weights resident in LDS (f16) ----------------
__global__ __launch_bounds__(512) void ode_kernel(
    const char* __restrict__ stg, const float* __restrict__ zc,
    const float* __restrict__ fc_w, const float* __restrict__ fc_b,
    float* __restrict__ out) {
  __shared__ __align__(16) unsigned char SHO[101632];
  const uint2* dr1s = (const uint2*)(SHO);
  const uint2* tau1s = (const uint2*)(SHO + 16384);
  const uint2* dr2s = (const uint2*)(SHO + 32768);
  const uint2* tau2s = (const uint2*)(SHO + 49152);
  const uint2* As = (const uint2*)(SHO + 65536);
  const float* fb = (const float*)(SHO + 73728);
  float* ZT = (float*)(SHO + 75776);
  float* HID = (float*)(SHO + 80128);
  float* DRV = (float*)(SHO + 88576);
  float* TAU = (float*)(SHO + 92928);
  float* ZA = (float*)(SHO + 97280);
  float4* ZTf = (float4*)ZT;
  float4* HIDf = (float4*)HID;

  const int t = threadIdx.x;
  const int b0 = blockIdx.x * 16;

  {
    const uint4* src = (const uint4*)stg;
    uint4* dst = (uint4*)SHO;
    for (int i = t; i < 4736; i += 512) dst[i] = src[i];
  }
  if (t < 256) ZTf[(t >> 4) * 17 + (t & 15)] = ((const float4*)(zc + (size_t)b0 * 64))[t];
  __syncthreads();

  const int bb = t >> 5;
  const int j4 = t & 31;
  const int xmask = j4 & 15;
  float tm = 0.f;

  for (int s = 0; s < 32; ++s) {
    {
      float4 a0 = zero4(), a1 = zero4(), a2 = zero4(), a3 = zero4();
#pragma unroll
      for (int k4 = 0; k4 < 16; ++k4) {
        float4 z4 = ZTf[bb * 17 + k4];
        int g = k4 ^ xmask;
        fma4(a0, z4, up4(dr1s[(j4) * 16 + g]));
        fma4(a1, z4, up4(dr1s[(j4 + 32) * 16 + g]));
        fma4(a2, z4, up4(dr1s[(j4 + 64) * 16 + g]));
        fma4(a3, z4, up4(dr1s[(j4 + 96) * 16 + g]));
      }
      HID[bb * 132 + j4] = tanhf(hsum4(a0) + fb[j4]);
      HID[bb * 132 + j4 + 32] = tanhf(hsum4(a1) + fb[j4 + 32]);
      HID[bb * 132 + j4 + 64] = tanhf(hsum4(a2) + fb[j4 + 64]);
      HID[bb * 132 + j4 + 96] = tanhf(hsum4(a3) + fb[j4 + 96]);
    }
    __syncthreads();
    {
      float4 a0 = zero4(), a1 = zero4();
#pragma unroll
      for (int k4 = 0; k4 < 32; ++k4) {
        float4 h4 = HIDf[bb * 33 + k4];
        int g = k4 ^ xmask;
        fma4(a0, h4, up4(dr2s[(j4) * 32 + g]));
        fma4(a1, h4, up4(dr2s[(j4 + 32) * 32 + g]));
      }
      float4 g0 = zero4(), g1 = zero4();
#pragma unroll
      for (int k4 = 0; k4 < 16; ++k4) {
        float4 z4 = ZTf[bb * 17 + k4];
        int g = k4 ^ xmask;
        fma4(g0, z4, up4(As[(j4) * 16 + g]));
        fma4(g1, z4, up4(As[(j4 + 32) * 16 + g]));
      }
      DRV[bb * 68 + j4] = hsum4(a0) + fb[256 + j4];
      DRV[bb * 68 + j4 + 32] = hsum4(a1) + fb[256 + j4 + 32];
      ZA[bb * 68 + j4] = hsum4(g0);
      ZA[bb * 68 + j4 + 32] = hsum4(g1);
    }
    __syncthreads();
    {
      float4 a0 = zero4(), a1 = zero4(), a2 = zero4(), a3 = zero4();
#pragma unroll
      for (int k4 = 0; k4 < 16; ++k4) {
        float4 z4 = ZTf[bb * 17 + k4];
        int g = k4 ^ xmask;
        fma4(a0, z4, up4(tau1s[(j4) * 16 + g]));
        fma4(a1, z4, up4(tau1s[(j4 + 32) * 16 + g]));
        fma4(a2, z4, up4(tau1s[(j4 + 64) * 16 + g]));
        fma4(a3, z4, up4(tau1s[(j4 + 96) * 16 + g]));
      }
      HID[bb * 132 + j4] = tanhf(hsum4(a0) + fmaf(tm, fb[384 + j4], fb[128 + j4]));
      HID[bb * 132 + j4 + 32] = tanhf(hsum4(a1) + fmaf(tm, fb[384 + j4 + 32], fb[128 + j4 + 32]));
      HID[bb * 132 + j4 + 64] = tanhf(hsum4(a2) + fmaf(tm, fb[384 + j4 + 64], fb[128 + j4 + 64]));
      HID[bb * 132 + j4 + 96] = tanhf(hsum4(a3) + fmaf(tm, fb[384 + j4 + 96], fb[128 + j4 + 96]));
    }
    __syncthreads();
    {
      float4 a0 = zero4(), a1 = zero4();
#pragma unroll
      for (int k4 = 0; k4 < 32; ++k4) {
        float4 h4 = HIDf[bb * 33 + k4];
        int g = k4 ^ xmask;
        fma4(a0, h4, up4(tau2s[(j4) * 32 + g]));
        fma4(a1, h4, up4(tau2s[(j4 + 32) * 32 + g]));
      }
      TAU[bb * 68 + j4] = hsum4(a0) + fb[320 + j4];
      TAU[bb * 68 + j4 + 32] = hsum4(a1) + fb[320 + j4 + 32];
    }
    __syncthreads();
    for (int idx = t; idx < 1024; idx += 512) {
      int bi = idx >> 6, d = idx & 63;
      float ztv = ZT[bi * 68 + d];
      float traw = TAU[bi * 68 + d];
      float sp = (traw > 15.f) ? traw : log1pf(expf(traw));
      float sg = 1.f / (1.f + expf(-(sp + 1e-6f)));
      float tau = fmaf(4.95f, sg, 0.05f);
      float inv = 1.f / tau;
      float dz = ZA[bi * 68 + d] + inv * (DRV[bi * 68 + d] - ztv);
      ZT[bi * 68 + d] = fmaf(0.03125f, dz, ztv);
    }
    __syncthreads();
    tm += 0.03125f;
  }

  for (int idx = t; idx < 768; idx += 512) {
    int bi = idx / 48, qd = idx - bi * 48;
    const float4* w = (const float4*)fc_w;
    float4 a0 = zero4(), a1 = zero4(), a2 = zero4(), a3 = zero4();
    for (int k4 = 0; k4 < 16; ++k4) {
      float4 z4 = ZTf[bi * 17 + k4];
      fma4(a0, z4, w[(qd * 4 + 0) * 16 + k4]);
      fma4(a1, z4, w[(qd * 4 + 1) * 16 + k4]);
      fma4(a2, z4, w[(qd * 4 + 2) * 16 + k4]);
      fma4(a3, z4, w[(qd * 4 + 3) * 16 + k4]);
    }
    float4 r;
    r.x = hsum4(a0) + fc_b[qd * 4 + 0];
    r.y = hsum4(a1) + fc_b[qd * 4 + 1];
    r.z = hsum4(a2) + fc_b[qd * 4 + 2];
    r.w = hsum4(a3) + fc_b[qd * 4 + 3];
    ((float4*)(out + (size_t)(b0 + bi) * 192))[qd] = r;
  }
}

extern "C" void kernel_launch(void* const* d_in, const int* in_sizes, int n_in,
                              void* d_out, int out_size, void* d_ws, size_t ws_size,
                              hipStream_t stream) {
  const float* x = (const float*)d_in[0];
  const float* conv_w = (const float*)d_in[1];
  const float* conv_b = (const float*)d_in[2];
  const float* cls = (const float*)d_in[3];
  const float* attn_w = (const float*)d_in[4];
  const float* attn_b = (const float*)d_in[5];
  const float* out_w = (const float*)d_in[6];
  const float* out_b = (const float*)d_in[7];
  const float* ln1_g = (const float*)d_in[8];
  const float* ln1_b = (const float*)d_in[9];
  const float* ln2_g = (const float*)d_in[10];
  const float* ln2_b = (const float*)d_in[11];
  const float* ff1_w = (const float*)d_in[12];
  const float* ff1_b = (const float*)d_in[13];
  const float* ff2_w = (const float*)d_in[14];
  const float* ff2_b = (const float*)d_in[15];
  const float* B_mat = (const float*)d_in[16];
  const float* dr1_w = (const float*)d_in[17];
  const float* dr1_b = (const float*)d_in[18];
  const float* dr2_w = (const float*)d_in[19];
  const float* dr2_b = (const float*)d_in[20];
  const float* tau1_w = (const float*)d_in[21];
  const float* tau1_b = (const float*)d_in[22];
  const float* tau2_w = (const float*)d_in[23];
  const float* tau2_b = (const float*)d_in[24];
  const float* fc_w = (const float*)d_in[25];
  const float* fc_b = (const float*)d_in[26];

  char* wsb = (char*)d_ws;
  float* zcb = (float*)(wsb + 75776);        // 4096*64 f32
  f16* tfw = (f16*)(wsb + 1124352);          // tf f16 weight blob (209408 B)

  prep_kernel<<<88, 64, 0, stream>>>(B_mat, dr1_w, dr1_b, dr2_w, dr2_b,
                                     tau1_w, tau1_b, tau2_w, tau2_b, wsb);
  prep_tf<<<410, 256, 0, stream>>>(conv_w, attn_w, out_w, ff1_w, ff2_w, tfw);
  tf_kernel<<<4096, 256, 0, stream>>>(x, tfw, conv_b, cls, attn_b, out_b,
                                      ln1_g, ln1_b, ln2_g, ln2_b, ff1_b, ff2_b, zcb);
  ode_kernel<<<256, 512, 0, stream>>>(wsb, zcb, fc_w, fc_b, (float*)d_out);
}

// Round 4
// 654.982 us; speedup vs baseline: 11.1481x; 1.8431x over previous
//
#include <hip/hip_runtime.h>
#include <hip/hip_fp16.h>
#include <math.h>

#define DEV static __device__ __forceinline__

typedef _Float16 f16;
typedef __attribute__((ext_vector_type(4))) _Float16 f16x4;
typedef __attribute__((ext_vector_type(8))) _Float16 f16x8;
typedef __attribute__((ext_vector_type(4))) float f32x4;

DEV f16x8 ld8(const f16* p) { return *(const f16x8*)p; }
DEV f32x4 mfma32(f16x8 a, f16x8 b, f32x4 c) {
  return __builtin_amdgcn_mfma_f32_16x16x32_f16(a, b, c, 0, 0, 0);
}
DEV float ftanh(float x) {
  float e = __expf(2.f * x);
  return 1.f - 2.f / (e + 1.f);
}

// ---------------- prep: pack ODE+FC weights f16 row-major [out][in] ----------------
// ws blob (bytes): 0 dr1h[128][64] | 16384 tau1h[128][64] | 32768 dr2h[64][128]
//  | 49152 tau2h[64][128] | 65536 Ah[64][64] | 73728 fch[192][64]
//  | 98304 fb f32[704]: dr1_b|tau1_b|dr2_b|tau2_b|t1t|fc_b
__global__ __launch_bounds__(64) void prep_kernel(
    const float* __restrict__ Bm,
    const float* __restrict__ dr1_w, const float* __restrict__ dr1_b,
    const float* __restrict__ dr2_w, const float* __restrict__ dr2_b,
    const float* __restrict__ tau1_w, const float* __restrict__ tau1_b,
    const float* __restrict__ tau2_w, const float* __restrict__ tau2_b,
    const float* __restrict__ fc_w, const float* __restrict__ fc_b,
    char* __restrict__ wsb) {
  f16* dr1h = (f16*)(wsb);
  f16* tau1h = (f16*)(wsb + 16384);
  f16* dr2h = (f16*)(wsb + 32768);
  f16* tau2h = (f16*)(wsb + 49152);
  f16* Ah = (f16*)(wsb + 65536);
  f16* fch = (f16*)(wsb + 73728);
  float* fb = (float*)(wsb + 98304);

  const int t = threadIdx.x, blk = blockIdx.x;
  if (blk < 16) {
    // A = -(B^T B): rows blk*4..+3, col group 4*(t&15)
    int row = blk * 4 + (t >> 4), c0 = 4 * (t & 15);
    float a0 = 0.f, a1 = 0.f, a2 = 0.f, a3 = 0.f;
    for (int m = 0; m < 64; ++m) {
      float br = Bm[m * 64 + row];
      a0 = fmaf(br, Bm[m * 64 + c0 + 0], a0);
      a1 = fmaf(br, Bm[m * 64 + c0 + 1], a1);
      a2 = fmaf(br, Bm[m * 64 + c0 + 2], a2);
      a3 = fmaf(br, Bm[m * 64 + c0 + 3], a3);
    }
    Ah[row * 64 + c0 + 0] = (f16)(-a0);
    Ah[row * 64 + c0 + 1] = (f16)(-a1);
    Ah[row * 64 + c0 + 2] = (f16)(-a2);
    Ah[row * 64 + c0 + 3] = (f16)(-a3);
  } else if (blk < 48) {
    int idx = (blk - 16) * 64 + t;  // 0..2047
    int row = idx >> 4, c0 = 4 * (idx & 15);
#pragma unroll
    for (int j = 0; j < 4; ++j) {
      dr1h[row * 64 + c0 + j] = (f16)dr1_w[row * 64 + c0 + j];
      tau1h[row * 64 + c0 + j] = (f16)tau1_w[row * 65 + c0 + j];
    }
  } else if (blk < 80) {
    int idx = (blk - 48) * 64 + t;  // 0..2047
    int row = idx >> 5, c0 = 4 * (idx & 31);
#pragma unroll
    for (int j = 0; j < 4; ++j) {
      dr2h[row * 128 + c0 + j] = (f16)dr2_w[row * 128 + c0 + j];
      tau2h[row * 128 + c0 + j] = (f16)tau2_w[row * 128 + c0 + j];
    }
  } else if (blk < 128) {
    int idx = (blk - 80) * 64 + t;  // 0..3071
    int row = idx >> 4, c0 = 4 * (idx & 15);
#pragma unroll
    for (int j = 0; j < 4; ++j)
      fch[row * 64 + c0 + j] = (f16)fc_w[row * 64 + c0 + j];
  } else {
    for (int i = (blk - 128) * 64 + t; i < 704; i += 128) {
      float v;
      if (i < 128) v = dr1_b[i];
      else if (i < 256) v = tau1_b[i - 128];
      else if (i < 320) v = dr2_b[i - 256];
      else if (i < 384) v = tau2_b[i - 320];
      else if (i < 512) v = tau1_w[(i - 384) * 65 + 64];  // t-column
      else v = fc_b[i - 512];
      fb[i] = v;
    }
  }
}

// ---------------- prep_tf: convert tf weights to f16, padded LDS-exact layouts ----
__global__ __launch_bounds__(256) void prep_tf(
    const float* __restrict__ conv_w, const float* __restrict__ attn_w,
    const float* __restrict__ out_w, const float* __restrict__ ff1_w,
    const float* __restrict__ ff2_w, f16* __restrict__ tfw) {
  int idx = blockIdx.x * 256 + threadIdx.x;
  if (idx < 8704) {
    int d = idx / 136, k = idx - d * 136;
    float v = (k < 128) ? conv_w[d * 128 + (k & 7) * 16 + (k >> 3)] : 0.f;
    tfw[idx] = (f16)v;
    return;
  }
  idx -= 8704;
  int l = idx / 32000;
  if (l >= 3) return;
  int r = idx - l * 32000;
  f16* ld = tfw + 8704 + l * 32000;
  float v;
  if (r < 13824) {
    int c = r / 4608, rr = r - c * 4608, j = rr / 72, k = rr - j * 72;
    v = (k < 64) ? attn_w[l * 12288 + (c * 64 + j) * 64 + k] : 0.f;
  } else if (r < 18432) {
    int rr = r - 13824, j = rr / 72, k = rr - j * 72;
    v = (k < 64) ? out_w[l * 4096 + j * 64 + k] : 0.f;
  } else if (r < 25344) {
    int rr = r - 18432, j = rr / 72, k = rr - j * 72;
    v = (k < 64) ? ff1_w[l * 6144 + j * 64 + k] : 0.f;
  } else {
    int rr = r - 25344, j = rr / 104, k = rr - j * 104;
    v = (k < 96) ? ff2_w[l * 6144 + j * 96 + k] : 0.f;
  }
  ld[r] = (f16)v;
}

// ---------------- transformer: MFMA, 1 block per batch, 4 waves (unchanged) -------
__global__ __launch_bounds__(256, 2) void tf_kernel(
    const float* __restrict__ x, const f16* __restrict__ tfw,
    const float* __restrict__ conv_b, const float* __restrict__ cls,
    const float* __restrict__ attn_b, const float* __restrict__ out_b,
    const float* __restrict__ ln1_g, const float* __restrict__ ln1_b,
    const float* __restrict__ ln2_g, const float* __restrict__ ln2_b,
    const float* __restrict__ ff1_b, const float* __restrict__ ff2_b,
    float* __restrict__ zc) {
  __shared__ __align__(16) unsigned char SH[77696];
  float* Zm = (float*)SH;
  f16* Zh = (f16*)(SH + 13056);
  f16* Qh = (f16*)(SH + 19968);
  f16* Kh = (f16*)(SH + 26880);
  f16* VT = (f16*)(SH + 33792);
  f16* oh = (f16*)(SH + 43008);
  f16* Wh = (f16*)(SH + 49920);
  f16* Sx = (f16*)(SH + 67328);
  float* lnm = (float*)(SH + 77312);
  float* lnr = (float*)(SH + 77504);

  const int t = threadIdx.x;
  const int b = blockIdx.x;
  const int w = t >> 6, lane = t & 63;
  const int c16 = lane & 15, q4 = lane >> 4;

  {
    const uint4* src = (const uint4*)tfw;
    uint4* dst = (uint4*)Wh;
    for (int i = t; i < 1088; i += 256) dst[i] = src[i];
    const float4* xg = (const float4*)(x + (size_t)b * 4096);
    for (int i = t; i < 1024; i += 256) {
      int n = i >> 5, j = i & 31;
      float4 v = xg[n * 32 + j];
      f16x4 h4 = {(f16)v.x, (f16)v.y, (f16)v.z, (f16)v.w};
      *(f16x4*)(Sx + n * 136 + j * 4) = h4;
    }
    for (int i = t; i < 1020; i += 256) Zm[33 * 68 + i] = 0.f;
    unsigned* zp = (unsigned*)(Zh + 33 * 72);
    for (int i = t; i < 540; i += 256) zp[i] = 0u;
    unsigned* vp = (unsigned*)VT;
    for (int i = t; i < 2304; i += 256) vp[i] = 0u;
    if (t < 64) {
      float v = cls[t] + ((t & 1) ? 1.0f : 0.0f);
      Zm[t] = v; Zh[t] = (f16)v;
    }
  }
  __syncthreads();

  {
    f16x8 bw[4];
#pragma unroll
    for (int kb = 0; kb < 4; ++kb)
      bw[kb] = ld8(Wh + (w * 16 + c16) * 136 + kb * 32 + q4 * 8);
    int d = w * 16 + c16;
    float cb = conv_b[d];
    float freq = __expf(-0.14391157f * (float)(d & ~1));
#pragma unroll
    for (int rt = 0; rt < 2; ++rt) {
      f32x4 acc = {};
#pragma unroll
      for (int kb = 0; kb < 4; ++kb)
        acc = mfma32(ld8(Sx + (rt * 16 + c16) * 136 + kb * 32 + q4 * 8), bw[kb], acc);
#pragma unroll
      for (int r = 0; r < 4; ++r) {
        int zr = rt * 16 + q4 * 4 + r + 1;
        float ang = (float)zr * freq;
        float pe = (d & 1) ? cosf(ang) : sinf(ang);
        float val = acc[r] + cb + pe;
        Zm[zr * 68 + d] = val;
        Zh[zr * 72 + d] = (f16)val;
      }
    }
  }
  __syncthreads();

  for (int l = 0; l < 3; ++l) {
    const f16* lw = tfw + 8704 + l * 32000;

    for (int c = 0; c < 3; ++c) {
      {
        const uint4* src = (const uint4*)(lw + c * 4608);
        uint4* dst = (uint4*)Wh;
        for (int i = t; i < 576; i += 256) dst[i] = src[i];
      }
      __syncthreads();
      {
        int j = w * 16 + c16;
        float bias = attn_b[l * 192 + c * 64 + j];
        f16x8 b0 = ld8(Wh + j * 72 + q4 * 8);
        f16x8 b1 = ld8(Wh + j * 72 + 32 + q4 * 8);
#pragma unroll
        for (int rt = 0; rt < 3; ++rt) {
          f32x4 acc = {};
          acc = mfma32(ld8(Zh + (rt * 16 + c16) * 72 + q4 * 8), b0, acc);
          acc = mfma32(ld8(Zh + (rt * 16 + c16) * 72 + 32 + q4 * 8), b1, acc);
          if (c == 0) {
#pragma unroll
            for (int r = 0; r < 4; ++r)
              Qh[(rt * 16 + q4 * 4 + r) * 72 + j] = (f16)((acc[r] + bias) * 0.25f);
          } else if (c == 1) {
#pragma unroll
            for (int r = 0; r < 4; ++r)
              Kh[(rt * 16 + q4 * 4 + r) * 72 + j] = (f16)(acc[r] + bias);
          } else {
            if (rt < 2) {
              f16x4 pv = {(f16)(acc[0] + bias), (f16)(acc[1] + bias),
                          (f16)(acc[2] + bias), (f16)(acc[3] + bias)};
              *(f16x4*)(VT + j * 72 + rt * 16 + q4 * 4) = pv;
            } else if (q4 == 0) {
              VT[j * 72 + 32] = (f16)(acc[0] + bias);
            }
          }
        }
      }
      __syncthreads();
    }

    f32x4 s[3][3];
    {
      f16x8 zf = {};
      f16x8 aq[3], bk[3];
#pragma unroll
      for (int rt = 0; rt < 3; ++rt)
        aq[rt] = (q4 < 2) ? ld8(Qh + (rt * 16 + c16) * 72 + w * 16 + q4 * 8) : zf;
#pragma unroll
      for (int ck = 0; ck < 3; ++ck)
        bk[ck] = (q4 < 2) ? ld8(Kh + (ck * 16 + c16) * 72 + w * 16 + q4 * 8) : zf;
#pragma unroll
      for (int rt = 0; rt < 3; ++rt)
#pragma unroll
        for (int ck = 0; ck < 3; ++ck) {
          f32x4 zz = {};
          s[rt][ck] = mfma32(aq[rt], bk[ck], zz);
        }
      unsigned* pp = (unsigned*)Wh;
      for (int i = t; i < 3840; i += 256) pp[i] = 0u;
    }
    __syncthreads();

    {
      f16* Ph = Wh + w * 1920;
#pragma unroll
      for (int rt = 0; rt < 3; ++rt) {
#pragma unroll
        for (int r = 0; r < 4; ++r) {
          float v0 = s[rt][0][r], v1 = s[rt][1][r];
          float v2 = (c16 == 0) ? s[rt][2][r] : -1e30f;
          float m = fmaxf(fmaxf(v0, v1), v2);
          m = fmaxf(m, __shfl_xor(m, 1));
          m = fmaxf(m, __shfl_xor(m, 2));
          m = fmaxf(m, __shfl_xor(m, 4));
          m = fmaxf(m, __shfl_xor(m, 8));
          float e0 = __expf(v0 - m), e1 = __expf(v1 - m);
          float e2 = (c16 == 0) ? __expf(v2 - m) : 0.f;
          float su = e0 + e1 + e2;
          su += __shfl_xor(su, 1);
          su += __shfl_xor(su, 2);
          su += __shfl_xor(su, 4);
          su += __shfl_xor(su, 8);
          float inv = 1.f / su;
          int i = rt * 16 + q4 * 4 + r;
          if (i < 33) {
            Ph[i * 40 + c16] = (f16)(e0 * inv);
            Ph[i * 40 + 16 + c16] = (f16)(e1 * inv);
            if (c16 == 0) Ph[i * 40 + 32] = (f16)(e2 * inv);
          }
        }
      }
    }
    __syncthreads();

    {
      const f16* Ph = Wh + w * 1920;
      int d = w * 16 + c16;
      f16x8 bv = ld8(VT + d * 72 + q4 * 8);
      float v32 = (float)VT[d * 72 + 32];
#pragma unroll
      for (int rt = 0; rt < 3; ++rt) {
        f32x4 acc = {};
        acc = mfma32(ld8(Ph + (rt * 16 + c16) * 40 + q4 * 8), bv, acc);
#pragma unroll
        for (int r = 0; r < 4; ++r) {
          int i = rt * 16 + q4 * 4 + r;
          float o = acc[r] + (float)Ph[i * 40 + 32] * v32;
          oh[i * 72 + d] = (f16)o;
        }
      }
    }
    __syncthreads();

    {
      const uint4* src = (const uint4*)(lw + 13824);
      uint4* dst = (uint4*)Wh;
      for (int i = t; i < 576; i += 256) dst[i] = src[i];
    }
    __syncthreads();

    {
      int d = w * 16 + c16;
      float bias = out_b[l * 64 + d];
      f16x8 b0 = ld8(Wh + d * 72 + q4 * 8);
      f16x8 b1 = ld8(Wh + d * 72 + 32 + q4 * 8);
#pragma unroll
      for (int rt = 0; rt < 3; ++rt) {
        f32x4 acc = {};
        acc = mfma32(ld8(oh + (rt * 16 + c16) * 72 + q4 * 8), b0, acc);
        acc = mfma32(ld8(oh + (rt * 16 + c16) * 72 + 32 + q4 * 8), b1, acc);
#pragma unroll
        for (int r = 0; r < 4; ++r) {
          int i = rt * 16 + q4 * 4 + r;
          if (i < 33) Zm[i * 68 + d] += acc[r] + bias;
        }
      }
    }
    __syncthreads();

    if (t < 132) {
      int row = t >> 2, l4 = t & 3;
      const float4* zr = (const float4*)(Zm + row * 68 + l4 * 16);
      float su = 0.f, ss = 0.f;
#pragma unroll
      for (int c4 = 0; c4 < 4; ++c4) {
        float4 v = zr[c4];
        su += (v.x + v.y) + (v.z + v.w);
        ss = fmaf(v.x, v.x, ss); ss = fmaf(v.y, v.y, ss);
        ss = fmaf(v.z, v.z, ss); ss = fmaf(v.w, v.w, ss);
      }
      su += __shfl_xor(su, 1); su += __shfl_xor(su, 2);
      ss += __shfl_xor(ss, 1); ss += __shfl_xor(ss, 2);
      float m = su * 0.015625f;
      float var = ss * 0.015625f - m * m;
      if (l4 == 0) { lnm[row] = m; lnr[row] = rsqrtf(var + 1e-5f); }
    }
    __syncthreads();

    {
      const uint4* src = (const uint4*)(lw + 18432);
      uint4* dst = (uint4*)Wh;
      for (int i = t; i < 864; i += 256) dst[i] = src[i];
      for (int idx = t; idx < 2112; idx += 256) {
        int i = idx >> 6, d = idx & 63;
        float val = (Zm[i * 68 + d] - lnm[i]) * lnr[i] * ln1_g[l * 64 + d] + ln1_b[l * 64 + d];
        Zm[i * 68 + d] = val;
        Zh[i * 72 + d] = (f16)val;
      }
    }
    __syncthreads();

    {
      f16* f1h = Sx;
      f16x8 a0[3], a1[3];
#pragma unroll
      for (int rt = 0; rt < 3; ++rt) {
        a0[rt] = ld8(Zh + (rt * 16 + c16) * 72 + q4 * 8);
        a1[rt] = ld8(Zh + (rt * 16 + c16) * 72 + 32 + q4 * 8);
      }
      for (int cc = w; cc < 6; cc += 4) {
        int j = cc * 16 + c16;
        float bias = ff1_b[l * 96 + j];
        f16x8 b0 = ld8(Wh + j * 72 + q4 * 8);
        f16x8 b1 = ld8(Wh + j * 72 + 32 + q4 * 8);
#pragma unroll
        for (int rt = 0; rt < 3; ++rt) {
          f32x4 acc = {};
          acc = mfma32(a0[rt], b0, acc);
          acc = mfma32(a1[rt], b1, acc);
#pragma unroll
          for (int r = 0; r < 4; ++r)
            f1h[(rt * 16 + q4 * 4 + r) * 104 + j] = (f16)fmaxf(acc[r] + bias, 0.f);
        }
      }
    }
    __syncthreads();

    {
      const uint4* src = (const uint4*)(lw + 25344);
      uint4* dst = (uint4*)Wh;
      for (int i = t; i < 832; i += 256) dst[i] = src[i];
    }
    __syncthreads();

    {
      const f16* f1h = Sx;
      int d = w * 16 + c16;
      float bias = ff2_b[l * 64 + d];
      f16x8 b0 = ld8(Wh + d * 104 + q4 * 8);
      f16x8 b1 = ld8(Wh + d * 104 + 32 + q4 * 8);
      f16x8 b2 = ld8(Wh + d * 104 + 64 + q4 * 8);
#pragma unroll
      for (int rt = 0; rt < 3; ++rt) {
        f32x4 acc = {};
        acc = mfma32(ld8(f1h + (rt * 16 + c16) * 104 + q4 * 8), b0, acc);
        acc = mfma32(ld8(f1h + (rt * 16 + c16) * 104 + 32 + q4 * 8), b1, acc);
        acc = mfma32(ld8(f1h + (rt * 16 + c16) * 104 + 64 + q4 * 8), b2, acc);
#pragma unroll
        for (int r = 0; r < 4; ++r) {
          int i = rt * 16 + q4 * 4 + r;
          if (i < 33) Zm[i * 68 + d] += acc[r] + bias;
        }
      }
    }
    __syncthreads();

    if (t < 132) {
      int row = t >> 2, l4 = t & 3;
      const float4* zr = (const float4*)(Zm + row * 68 + l4 * 16);
      float su = 0.f, ss = 0.f;
#pragma unroll
      for (int c4 = 0; c4 < 4; ++c4) {
        float4 v = zr[c4];
        su += (v.x + v.y) + (v.z + v.w);
        ss = fmaf(v.x, v.x, ss); ss = fmaf(v.y, v.y, ss);
        ss = fmaf(v.z, v.z, ss); ss = fmaf(v.w, v.w, ss);
      }
      su += __shfl_xor(su, 1); su += __shfl_xor(su, 2);
      ss += __shfl_xor(ss, 1); ss += __shfl_xor(ss, 2);
      float m = su * 0.015625f;
      float var = ss * 0.015625f - m * m;
      if (l4 == 0) { lnm[row] = m; lnr[row] = rsqrtf(var + 1e-5f); }
    }
    __syncthreads();

    for (int idx = t; idx < 2112; idx += 256) {
      int i = idx >> 6, d = idx & 63;
      float val = (Zm[i * 68 + d] - lnm[i]) * lnr[i] * ln2_g[l * 64 + d] + ln2_b[l * 64 + d];
      Zm[i * 68 + d] = val;
      Zh[i * 72 + d] = (f16)val;
      if (l == 2 && i == 0) zc[(size_t)b * 64 + d] = val;
    }
    __syncthreads();
  }
}

// ---------------- ODE: MFMA, 1 wave = 16 batch rows, weights in VGPRs ----------------
__global__ __launch_bounds__(64) void ode_kernel(
    const char* __restrict__ wsb, const float* __restrict__ zc,
    float* __restrict__ out) {
  const f16* dr1h = (const f16*)(wsb);
  const f16* tau1h = (const f16*)(wsb + 16384);
  const f16* dr2h = (const f16*)(wsb + 32768);
  const f16* tau2h = (const f16*)(wsb + 49152);
  const f16* Ah = (const f16*)(wsb + 65536);
  const f16* fch = (const f16*)(wsb + 73728);
  const float* fb = (const float*)(wsb + 98304);

  __shared__ __align__(16) f16 ztL[16 * 64];
  __shared__ __align__(16) f16 hdL[16 * 128];
  __shared__ __align__(16) f16 htL[16 * 128];

  const int lane = threadIdx.x;
  const int c16 = lane & 15, q4 = lane >> 4;
  const int b0 = blockIdx.x * 16;
  const int wsz = (c16 & 7) << 3;  // read-side swizzle for row c16

  // ---- weight fragments (persistent in VGPRs) ----
  f16x8 dr1B[8][2], tau1B[8][2], dr2B[4][4], tau2B[4][4], AB[4][2];
#pragma unroll
  for (int ct = 0; ct < 8; ++ct)
#pragma unroll
    for (int kb = 0; kb < 2; ++kb) {
      dr1B[ct][kb] = ld8(dr1h + (ct * 16 + c16) * 64 + kb * 32 + q4 * 8);
      tau1B[ct][kb] = ld8(tau1h + (ct * 16 + c16) * 64 + kb * 32 + q4 * 8);
    }
#pragma unroll
  for (int ct = 0; ct < 4; ++ct) {
#pragma unroll
    for (int kb = 0; kb < 4; ++kb) {
      dr2B[ct][kb] = ld8(dr2h + (ct * 16 + c16) * 128 + kb * 32 + q4 * 8);
      tau2B[ct][kb] = ld8(tau2h + (ct * 16 + c16) * 128 + kb * 32 + q4 * 8);
    }
#pragma unroll
    for (int kb = 0; kb < 2; ++kb)
      AB[ct][kb] = ld8(Ah + (ct * 16 + c16) * 64 + kb * 32 + q4 * 8);
  }
  float dr1b[8], tau1b[8], t1t[8];
#pragma unroll
  for (int ct = 0; ct < 8; ++ct) {
    dr1b[ct] = fb[ct * 16 + c16];
    tau1b[ct] = fb[128 + ct * 16 + c16];
    t1t[ct] = fb[384 + ct * 16 + c16];
  }
  float dr2b[4], tau2b[4];
#pragma unroll
  for (int ct = 0; ct < 4; ++ct) {
    dr2b[ct] = fb[256 + ct * 16 + c16];
    tau2b[ct] = fb[320 + ct * 16 + c16];
  }

  // ---- zt master (f32, D-layout: row=q4*4+r, col=ct*16+c16) ----
  float zt[4][4];
#pragma unroll
  for (int ct = 0; ct < 4; ++ct)
#pragma unroll
    for (int r = 0; r < 4; ++r)
      zt[ct][r] = zc[(size_t)(b0 + q4 * 4 + r) * 64 + ct * 16 + c16];

  float tm = 0.f;
  for (int s = 0; s < 32; ++s) {
    // zt -> A-layout (f16, XOR-swizzled)
#pragma unroll
    for (int ct = 0; ct < 4; ++ct)
#pragma unroll
      for (int r = 0; r < 4; ++r) {
        int row = q4 * 4 + r;
        ztL[row * 64 + ((ct * 16 + c16) ^ ((row & 7) << 3))] = (f16)zt[ct][r];
      }
    __syncthreads();
    f16x8 ztA[2];
#pragma unroll
    for (int kb = 0; kb < 2; ++kb)
      ztA[kb] = ld8(ztL + c16 * 64 + ((kb * 32 + q4 * 8) ^ wsz));

    // hid_drive / hid_tau
#pragma unroll
    for (int ct = 0; ct < 8; ++ct) {
      f32x4 ad = {}, at = {};
      ad = mfma32(ztA[0], dr1B[ct][0], ad);
      ad = mfma32(ztA[1], dr1B[ct][1], ad);
      at = mfma32(ztA[0], tau1B[ct][0], at);
      at = mfma32(ztA[1], tau1B[ct][1], at);
      float bd = dr1b[ct];
      float bt = fmaf(tm, t1t[ct], tau1b[ct]);
#pragma unroll
      for (int r = 0; r < 4; ++r) {
        int row = q4 * 4 + r;
        int off = row * 128 + ((ct * 16 + c16) ^ ((row & 7) << 3));
        hdL[off] = (f16)ftanh(ad[r] + bd);
        htL[off] = (f16)ftanh(at[r] + bt);
      }
    }
    __syncthreads();
    f16x8 hdA[4], htA[4];
#pragma unroll
    for (int kb = 0; kb < 4; ++kb) {
      int ko = c16 * 128 + ((kb * 32 + q4 * 8) ^ wsz);
      hdA[kb] = ld8(hdL + ko);
      htA[kb] = ld8(htL + ko);
    }

    // drive / tau_raw / zA + Euler update
#pragma unroll
    for (int ct = 0; ct < 4; ++ct) {
      f32x4 dv = {}, tr = {}, za = {};
#pragma unroll
      for (int kb = 0; kb < 4; ++kb) {
        dv = mfma32(hdA[kb], dr2B[ct][kb], dv);
        tr = mfma32(htA[kb], tau2B[ct][kb], tr);
      }
      za = mfma32(ztA[0], AB[ct][0], za);
      za = mfma32(ztA[1], AB[ct][1], za);
#pragma unroll
      for (int r = 0; r < 4; ++r) {
        float traw = tr[r] + tau2b[ct];
        float sp = (traw > 15.f) ? traw : log1pf(__expf(traw));
        float sg = 1.f / (1.f + __expf(-(sp + 1e-6f)));
        float tau = fmaf(4.95f, sg, 0.05f);
        float inv = 1.f / tau;
        float ztv = zt[ct][r];
        float dz = za[r] + inv * ((dv[r] + dr2b[ct]) - ztv);
        zt[ct][r] = fmaf(0.03125f, dz, ztv);
      }
    }
    tm += 0.03125f;
    __syncthreads();
  }

  // ---- final FC (fused) ----
#pragma unroll
  for (int ct = 0; ct < 4; ++ct)
#pragma unroll
    for (int r = 0; r < 4; ++r) {
      int row = q4 * 4 + r;
      ztL[row * 64 + ((ct * 16 + c16) ^ ((row & 7) << 3))] = (f16)zt[ct][r];
    }
  __syncthreads();
  f16x8 zA2[2];
#pragma unroll
  for (int kb = 0; kb < 2; ++kb)
    zA2[kb] = ld8(ztL + c16 * 64 + ((kb * 32 + q4 * 8) ^ wsz));
#pragma unroll
  for (int ct = 0; ct < 12; ++ct) {
    f32x4 acc = {};
    acc = mfma32(zA2[0], ld8(fch + (ct * 16 + c16) * 64 + q4 * 8), acc);
    acc = mfma32(zA2[1], ld8(fch + (ct * 16 + c16) * 64 + 32 + q4 * 8), acc);
    float bias = fb[512 + ct * 16 + c16];
#pragma unroll
    for (int r = 0; r < 4; ++r)
      out[(size_t)(b0 + q4 * 4 + r) * 192 + ct * 16 + c16] = acc[r] + bias;
  }
}

extern "C" void kernel_launch(void* const* d_in, const int* in_sizes, int n_in,
                              void* d_out, int out_size, void* d_ws, size_t ws_size,
                              hipStream_t stream) {
  const float* x = (const float*)d_in[0];
  const float* conv_w = (const float*)d_in[1];
  const float* conv_b = (const float*)d_in[2];
  const float* cls = (const float*)d_in[3];
  const float* attn_w = (const float*)d_in[4];
  const float* attn_b = (const float*)d_in[5];
  const float* out_w = (const float*)d_in[6];
  const float* out_b = (const float*)d_in[7];
  const float* ln1_g = (const float*)d_in[8];
  const float* ln1_b = (const float*)d_in[9];
  const float* ln2_g = (const float*)d_in[10];
  const float* ln2_b = (const float*)d_in[11];
  const float* ff1_w = (const float*)d_in[12];
  const float* ff1_b = (const float*)d_in[13];
  const float* ff2_w = (const float*)d_in[14];
  const float* ff2_b = (const float*)d_in[15];
  const float* B_mat = (const float*)d_in[16];
  const float* dr1_w = (const float*)d_in[17];
  const float* dr1_b = (const float*)d_in[18];
  const float* dr2_w = (const float*)d_in[19];
  const float* dr2_b = (const float*)d_in[20];
  const float* tau1_w = (const float*)d_in[21];
  const float* tau1_b = (const float*)d_in[22];
  const float* tau2_w = (const float*)d_in[23];
  const float* tau2_b = (const float*)d_in[24];
  const float* fc_w = (const float*)d_in[25];
  const float* fc_b = (const float*)d_in[26];

  char* wsb = (char*)d_ws;
  float* zcb = (float*)(wsb + 101376);   // 4096*64 f32 (1048576 B)
  f16* tfw = (f16*)(wsb + 1149952);      // tf f16 weight blob (209408 B)

  prep_kernel<<<130, 64, 0, stream>>>(B_mat, dr1_w, dr1_b, dr2_w, dr2_b,
                                      tau1_w, tau1_b, tau2_w, tau2_b,
                                      fc_w, fc_b, wsb);
  prep_tf<<<410, 256, 0, stream>>>(conv_w, attn_w, out_w, ff1_w, ff2_w, tfw);
  tf_kernel<<<4096, 256, 0, stream>>>(x, tfw, conv_b, cls, attn_b, out_b,
                                      ln1_g, ln1_b, ln2_g, ln2_b, ff1_b, ff2_b, zcb);
  ode_kernel<<<256, 64, 0, stream>>>(wsb, zcb, (float*)d_out);
}

// Round 5
// 539.975 us; speedup vs baseline: 13.5225x; 1.2130x over previous
//
#include <hip/hip_runtime.h>
#include <hip/hip_fp16.h>
#include <math.h>

#define DEV static __device__ __forceinline__

typedef _Float16 f16;
typedef __attribute__((ext_vector_type(4))) _Float16 f16x4;
typedef __attribute__((ext_vector_type(8))) _Float16 f16x8;
typedef __attribute__((ext_vector_type(4))) float f32x4;

DEV f16x8 ld8(const f16* p) { return *(const f16x8*)p; }
DEV f32x4 mfma32(f16x8 a, f16x8 b, f32x4 c) {
  return __builtin_amdgcn_mfma_f32_16x16x32_f16(a, b, c, 0, 0, 0);
}
DEV float ftanh(float x) {
  float e = __expf(2.f * x);
  return 1.f - 2.f / (e + 1.f);
}

// ---------------- prep: pack ODE+FC weights f16 row-major [out][in] ----------------
// ws blob (bytes): 0 dr1h[128][64] | 16384 tau1h[128][64] | 32768 dr2h[64][128]
//  | 49152 tau2h[64][128] | 65536 Ah[64][64] | 73728 fch[192][64]
//  | 98304 fb f32[704]: dr1_b|tau1_b|dr2_b|tau2_b|t1t|fc_b
__global__ __launch_bounds__(64) void prep_kernel(
    const float* __restrict__ Bm,
    const float* __restrict__ dr1_w, const float* __restrict__ dr1_b,
    const float* __restrict__ dr2_w, const float* __restrict__ dr2_b,
    const float* __restrict__ tau1_w, const float* __restrict__ tau1_b,
    const float* __restrict__ tau2_w, const float* __restrict__ tau2_b,
    const float* __restrict__ fc_w, const float* __restrict__ fc_b,
    char* __restrict__ wsb) {
  f16* dr1h = (f16*)(wsb);
  f16* tau1h = (f16*)(wsb + 16384);
  f16* dr2h = (f16*)(wsb + 32768);
  f16* tau2h = (f16*)(wsb + 49152);
  f16* Ah = (f16*)(wsb + 65536);
  f16* fch = (f16*)(wsb + 73728);
  float* fb = (float*)(wsb + 98304);

  const int t = threadIdx.x, blk = blockIdx.x;
  if (blk < 16) {
    int row = blk * 4 + (t >> 4), c0 = 4 * (t & 15);
    float a0 = 0.f, a1 = 0.f, a2 = 0.f, a3 = 0.f;
    for (int m = 0; m < 64; ++m) {
      float br = Bm[m * 64 + row];
      a0 = fmaf(br, Bm[m * 64 + c0 + 0], a0);
      a1 = fmaf(br, Bm[m * 64 + c0 + 1], a1);
      a2 = fmaf(br, Bm[m * 64 + c0 + 2], a2);
      a3 = fmaf(br, Bm[m * 64 + c0 + 3], a3);
    }
    Ah[row * 64 + c0 + 0] = (f16)(-a0);
    Ah[row * 64 + c0 + 1] = (f16)(-a1);
    Ah[row * 64 + c0 + 2] = (f16)(-a2);
    Ah[row * 64 + c0 + 3] = (f16)(-a3);
  } else if (blk < 48) {
    int idx = (blk - 16) * 64 + t;
    int row = idx >> 4, c0 = 4 * (idx & 15);
#pragma unroll
    for (int j = 0; j < 4; ++j) {
      dr1h[row * 64 + c0 + j] = (f16)dr1_w[row * 64 + c0 + j];
      tau1h[row * 64 + c0 + j] = (f16)tau1_w[row * 65 + c0 + j];
    }
  } else if (blk < 80) {
    int idx = (blk - 48) * 64 + t;
    int row = idx >> 5, c0 = 4 * (idx & 31);
#pragma unroll
    for (int j = 0; j < 4; ++j) {
      dr2h[row * 128 + c0 + j] = (f16)dr2_w[row * 128 + c0 + j];
      tau2h[row * 128 + c0 + j] = (f16)tau2_w[row * 128 + c0 + j];
    }
  } else if (blk < 128) {
    int idx = (blk - 80) * 64 + t;
    int row = idx >> 4, c0 = 4 * (idx & 15);
#pragma unroll
    for (int j = 0; j < 4; ++j)
      fch[row * 64 + c0 + j] = (f16)fc_w[row * 64 + c0 + j];
  } else {
    for (int i = (blk - 128) * 64 + t; i < 704; i += 128) {
      float v;
      if (i < 128) v = dr1_b[i];
      else if (i < 256) v = tau1_b[i - 128];
      else if (i < 320) v = dr2_b[i - 256];
      else if (i < 384) v = tau2_b[i - 320];
      else if (i < 512) v = tau1_w[(i - 384) * 65 + 64];
      else v = fc_b[i - 512];
      fb[i] = v;
    }
  }
}

// ---------------- prep_tf: tf weights -> f16, plain row-major layouts ----------------
// tfw (f16): 0 CW[64][128] | per layer l at 8192 + l*28672:
//   +0 qkvW[192][64] | +12288 outW[64][64] | +16384 ff1W[96][64] | +22528 ff2W[64][96]
__global__ __launch_bounds__(256) void prep_tf(
    const float* __restrict__ conv_w, const float* __restrict__ attn_w,
    const float* __restrict__ out_w, const float* __restrict__ ff1_w,
    const float* __restrict__ ff2_w, f16* __restrict__ tfw) {
  int idx = blockIdx.x * 256 + threadIdx.x;
  if (idx >= 94208) return;
  float v;
  if (idx < 8192) {
    int dd = idx >> 7, k = idx & 127;
    v = conv_w[dd * 128 + (k & 7) * 16 + (k >> 3)];  // CW[d][p*8+c]
  } else {
    int r = idx - 8192;
    int l = r / 28672, q = r - l * 28672;
    if (q < 12288) v = attn_w[l * 12288 + q];
    else if (q < 16384) v = out_w[l * 4096 + (q - 12288)];
    else if (q < 22528) v = ff1_w[l * 6144 + (q - 16384)];
    else v = ff2_w[l * 6144 + (q - 22528)];
  }
  tfw[idx] = (f16)v;
}

// ---------------- transformer v2: weights from L2, 7 barriers/layer, 3 blocks/CU ----
// LDS (bytes): Zm f32[33][68] @0 | Zh f16[48][72] @8976 | Qh/oh @15888 | Kh @22800
//  | VT f16[64][56] @29712 | P f16[4][48][40] @36880 | psum f32[192] @52240 | psq @53008
//  aliases: Sx f16[32][136] @15888 (prologue) ; f1h f16[48][104] @22800 (ff phase)
__global__ __launch_bounds__(256, 3) void tf_kernel(
    const float* __restrict__ x, const f16* __restrict__ tfw,
    const float* __restrict__ conv_b, const float* __restrict__ cls,
    const float* __restrict__ attn_b, const float* __restrict__ out_b,
    const float* __restrict__ ln1_g, const float* __restrict__ ln1_b,
    const float* __restrict__ ln2_g, const float* __restrict__ ln2_b,
    const float* __restrict__ ff1_b, const float* __restrict__ ff2_b,
    float* __restrict__ zc) {
  __shared__ __align__(16) unsigned char SH[53776];
  float* Zm = (float*)SH;
  f16* Zh = (f16*)(SH + 8976);
  f16* Qh = (f16*)(SH + 15888);
  f16* Kh = (f16*)(SH + 22800);
  f16* VT = (f16*)(SH + 29712);
  f16* P = (f16*)(SH + 36880);
  float* psum = (float*)(SH + 52240);
  float* psq = (float*)(SH + 53008);
  f16* Sx = (f16*)(SH + 15888);
  f16* f1h = (f16*)(SH + 22800);
  f16* oh = Qh;

  const int t = threadIdx.x;
  const int b = blockIdx.x;
  const int w = t >> 6, lane = t & 63;
  const int c16 = lane & 15, q4 = lane >> 4;
  const int d = w * 16 + c16;

  // ---- prologue: x->Sx(f16), zero Zh pads + P, cls row ----
  {
    const float4* xg = (const float4*)(x + (size_t)b * 4096);
    for (int i = t; i < 1024; i += 256) {
      int n = i >> 5, jj = i & 31;
      float4 v = xg[i];
      *(f16x4*)(Sx + n * 136 + jj * 4) = f16x4{(f16)v.x, (f16)v.y, (f16)v.z, (f16)v.w};
    }
    unsigned* zp = (unsigned*)(Zh + 33 * 72);
    for (int i = t; i < 540; i += 256) zp[i] = 0u;
    uint4 z4{0, 0, 0, 0};
    uint4* pp = (uint4*)P;
    for (int i = t; i < 960; i += 256) pp[i] = z4;
    if (t < 64) {
      float v = cls[t] + ((t & 1) ? 1.0f : 0.0f);
      Zm[t] = v; Zh[t] = (f16)v;
    }
  }
  __syncthreads();

  // ---- patch embed (CW from L2) + pos enc ----
  {
    f16x8 bw[4];
#pragma unroll
    for (int kb = 0; kb < 4; ++kb)
      bw[kb] = ld8(tfw + d * 128 + kb * 32 + q4 * 8);
    float cb = conv_b[d];
    float freq = __expf(-0.14391157f * (float)(d & ~1));
#pragma unroll
    for (int rt = 0; rt < 2; ++rt) {
      f32x4 acc = {};
#pragma unroll
      for (int kb = 0; kb < 4; ++kb)
        acc = mfma32(ld8(Sx + (rt * 16 + c16) * 136 + kb * 32 + q4 * 8), bw[kb], acc);
#pragma unroll
      for (int r = 0; r < 4; ++r) {
        int zr = rt * 16 + q4 * 4 + r + 1;
        float ang = (float)zr * freq;
        float pe = (d & 1) ? cosf(ang) : sinf(ang);
        float val = acc[r] + cb + pe;
        Zm[zr * 68 + d] = val;
        Zh[zr * 72 + d] = (f16)val;
      }
    }
  }
  __syncthreads();

  for (int l = 0; l < 3; ++l) {
    const f16* lw = tfw + 8192 + l * 28672;

    // ---- phase 1: qkv (weights from L2) ----
    {
      f16x8 wq0 = ld8(lw + d * 64 + q4 * 8);
      f16x8 wq1 = ld8(lw + d * 64 + 32 + q4 * 8);
      f16x8 wk0 = ld8(lw + (64 + d) * 64 + q4 * 8);
      f16x8 wk1 = ld8(lw + (64 + d) * 64 + 32 + q4 * 8);
      f16x8 wv0 = ld8(lw + (128 + d) * 64 + q4 * 8);
      f16x8 wv1 = ld8(lw + (128 + d) * 64 + 32 + q4 * 8);
      float bq = attn_b[l * 192 + d];
      float bk = attn_b[l * 192 + 64 + d];
      float bv = attn_b[l * 192 + 128 + d];
#pragma unroll
      for (int rt = 0; rt < 3; ++rt) {
        f16x8 a0 = ld8(Zh + (rt * 16 + c16) * 72 + q4 * 8);
        f16x8 a1 = ld8(Zh + (rt * 16 + c16) * 72 + 32 + q4 * 8);
        f32x4 aq = {}, ak = {}, av = {};
        aq = mfma32(a0, wq0, aq); aq = mfma32(a1, wq1, aq);
        ak = mfma32(a0, wk0, ak); ak = mfma32(a1, wk1, ak);
        av = mfma32(a0, wv0, av); av = mfma32(a1, wv1, av);
#pragma unroll
        for (int r = 0; r < 4; ++r) {
          int i = rt * 16 + q4 * 4 + r;
          Qh[i * 72 + d] = (f16)((aq[r] + bq) * 0.25f);
          Kh[i * 72 + d] = (f16)(ak[r] + bk);
        }
        if (rt < 2) {
          *(f16x4*)(VT + d * 56 + rt * 16 + q4 * 4) =
              f16x4{(f16)(av[0] + bv), (f16)(av[1] + bv),
                    (f16)(av[2] + bv), (f16)(av[3] + bv)};
        } else if (q4 == 0) {
          VT[d * 56 + 32] = (f16)(av[0] + bv);
        }
      }
    }
    __syncthreads();

    // ---- phase 2: scores + softmax + PV (wave-private, no internal barriers) ----
    {
      f16x8 zf = {};
      f16x8 aq[3], bkk[3];
#pragma unroll
      for (int rt = 0; rt < 3; ++rt)
        aq[rt] = (q4 < 2) ? ld8(Qh + (rt * 16 + c16) * 72 + w * 16 + q4 * 8) : zf;
#pragma unroll
      for (int ck = 0; ck < 3; ++ck)
        bkk[ck] = (q4 < 2) ? ld8(Kh + (ck * 16 + c16) * 72 + w * 16 + q4 * 8) : zf;
      f32x4 s[3][3];
#pragma unroll
      for (int rt = 0; rt < 3; ++rt)
#pragma unroll
        for (int ck = 0; ck < 3; ++ck) {
          f32x4 zz = {};
          s[rt][ck] = mfma32(aq[rt], bkk[ck], zz);
        }
      f16* Ph = P + w * 1920;
#pragma unroll
      for (int rt = 0; rt < 3; ++rt) {
#pragma unroll
        for (int r = 0; r < 4; ++r) {
          int i = rt * 16 + q4 * 4 + r;
          float v0 = s[rt][0][r], v1 = s[rt][1][r];
          float v2 = (c16 == 0) ? s[rt][2][r] : -1e30f;  // only kk=32 real in tile 2
          float m = fmaxf(fmaxf(v0, v1), v2);
          m = fmaxf(m, __shfl_xor(m, 1));
          m = fmaxf(m, __shfl_xor(m, 2));
          m = fmaxf(m, __shfl_xor(m, 4));
          m = fmaxf(m, __shfl_xor(m, 8));
          float e0 = __expf(v0 - m), e1 = __expf(v1 - m);
          float e2 = (c16 == 0) ? __expf(v2 - m) : 0.f;
          float su = e0 + e1 + e2;
          su += __shfl_xor(su, 1); su += __shfl_xor(su, 2);
          su += __shfl_xor(su, 4); su += __shfl_xor(su, 8);
          float inv = 1.f / su;
          if (i < 33) {
            Ph[i * 40 + c16] = (f16)(e0 * inv);
            Ph[i * 40 + 16 + c16] = (f16)(e1 * inv);
            if (c16 == 0) Ph[i * 40 + 32] = (f16)(e2 * inv);
          }
        }
      }
      // PV: same wave reads its own P (lgkmcnt orders write->read)
      f16x8 bv = ld8(VT + d * 56 + q4 * 8);
      float v32 = (float)VT[d * 56 + 32];
#pragma unroll
      for (int rt = 0; rt < 3; ++rt) {
        f32x4 acc = {};
        acc = mfma32(ld8(Ph + (rt * 16 + c16) * 40 + q4 * 8), bv, acc);
#pragma unroll
        for (int r = 0; r < 4; ++r) {
          int i = rt * 16 + q4 * 4 + r;
          oh[i * 72 + d] = (f16)(acc[r] + (float)Ph[i * 40 + 32] * v32);
        }
      }
    }
    __syncthreads();

    // ---- phase 3: out-proj + residual + LN1 partials ----
    {
      const f16* ow = lw + 12288;
      f16x8 b0 = ld8(ow + d * 64 + q4 * 8);
      f16x8 b1 = ld8(ow + d * 64 + 32 + q4 * 8);
      float bias = out_b[l * 64 + d];
#pragma unroll
      for (int rt = 0; rt < 3; ++rt) {
        f32x4 acc = {};
        acc = mfma32(ld8(oh + (rt * 16 + c16) * 72 + q4 * 8), b0, acc);
        acc = mfma32(ld8(oh + (rt * 16 + c16) * 72 + 32 + q4 * 8), b1, acc);
#pragma unroll
        for (int r = 0; r < 4; ++r) {
          int i = rt * 16 + q4 * 4 + r;
          float val = 0.f;
          if (i < 33) {
            val = Zm[i * 68 + d] + acc[r] + bias;
            Zm[i * 68 + d] = val;
          }
          float vs = val, vq = val * val;
          vs += __shfl_xor(vs, 1); vq += __shfl_xor(vq, 1);
          vs += __shfl_xor(vs, 2); vq += __shfl_xor(vq, 2);
          vs += __shfl_xor(vs, 4); vq += __shfl_xor(vq, 4);
          vs += __shfl_xor(vs, 8); vq += __shfl_xor(vq, 8);
          if (c16 == 0 && i < 33) { psum[w * 48 + i] = vs; psq[w * 48 + i] = vq; }
        }
      }
    }
    __syncthreads();

    // ---- phase 4: norm1 ----
    for (int idx = t; idx < 2112; idx += 256) {
      int i = idx >> 6, dd = idx & 63;
      float m = (psum[i] + psum[48 + i] + psum[96 + i] + psum[144 + i]) * 0.015625f;
      float sq = (psq[i] + psq[48 + i] + psq[96 + i] + psq[144 + i]) * 0.015625f;
      float rr = rsqrtf(sq - m * m + 1e-5f);
      float val = (Zm[i * 68 + dd] - m) * rr * ln1_g[l * 64 + dd] + ln1_b[l * 64 + dd];
      Zm[i * 68 + dd] = val;
      Zh[i * 72 + dd] = (f16)val;
    }
    __syncthreads();

    // ---- phase 5: ff1 ----
    {
      const f16* fw = lw + 16384;
      f16x8 a0[3], a1[3];
#pragma unroll
      for (int rt = 0; rt < 3; ++rt) {
        a0[rt] = ld8(Zh + (rt * 16 + c16) * 72 + q4 * 8);
        a1[rt] = ld8(Zh + (rt * 16 + c16) * 72 + 32 + q4 * 8);
      }
      for (int cc = w; cc < 6; cc += 4) {
        int jj = cc * 16 + c16;
        float bias = ff1_b[l * 96 + jj];
        f16x8 b0 = ld8(fw + jj * 64 + q4 * 8);
        f16x8 b1 = ld8(fw + jj * 64 + 32 + q4 * 8);
#pragma unroll
        for (int rt = 0; rt < 3; ++rt) {
          f32x4 acc = {};
          acc = mfma32(a0[rt], b0, acc);
          acc = mfma32(a1[rt], b1, acc);
#pragma unroll
          for (int r = 0; r < 4; ++r)
            f1h[(rt * 16 + q4 * 4 + r) * 104 + jj] = (f16)fmaxf(acc[r] + bias, 0.f);
        }
      }
    }
    __syncthreads();

    // ---- phase 6: ff2 + residual + LN2 partials ----
    {
      const f16* fw = lw + 22528;
      f16x8 b0 = ld8(fw + d * 96 + q4 * 8);
      f16x8 b1 = ld8(fw + d * 96 + 32 + q4 * 8);
      f16x8 b2 = ld8(fw + d * 96 + 64 + q4 * 8);
      float bias = ff2_b[l * 64 + d];
#pragma unroll
      for (int rt = 0; rt < 3; ++rt) {
        f32x4 acc = {};
        acc = mfma32(ld8(f1h + (rt * 16 + c16) * 104 + q4 * 8), b0, acc);
        acc = mfma32(ld8(f1h + (rt * 16 + c16) * 104 + 32 + q4 * 8), b1, acc);
        acc = mfma32(ld8(f1h + (rt * 16 + c16) * 104 + 64 + q4 * 8), b2, acc);
#pragma unroll
        for (int r = 0; r < 4; ++r) {
          int i = rt * 16 + q4 * 4 + r;
          float val = 0.f;
          if (i < 33) {
            val = Zm[i * 68 + d] + acc[r] + bias;
            Zm[i * 68 + d] = val;
          }
          float vs = val, vq = val * val;
          vs += __shfl_xor(vs, 1); vq += __shfl_xor(vq, 1);
          vs += __shfl_xor(vs, 2); vq += __shfl_xor(vq, 2);
          vs += __shfl_xor(vs, 4); vq += __shfl_xor(vq, 4);
          vs += __shfl_xor(vs, 8); vq += __shfl_xor(vq, 8);
          if (c16 == 0 && i < 33) { psum[w * 48 + i] = vs; psq[w * 48 + i] = vq; }
        }
      }
    }
    __syncthreads();

    // ---- phase 7: norm2 (+ zc on last layer) ----
    for (int idx = t; idx < 2112; idx += 256) {
      int i = idx >> 6, dd = idx & 63;
      float m = (psum[i] + psum[48 + i] + psum[96 + i] + psum[144 + i]) * 0.015625f;
      float sq = (psq[i] + psq[48 + i] + psq[96 + i] + psq[144 + i]) * 0.015625f;
      float rr = rsqrtf(sq - m * m + 1e-5f);
      float val = (Zm[i * 68 + dd] - m) * rr * ln2_g[l * 64 + dd] + ln2_b[l * 64 + dd];
      Zm[i * 68 + dd] = val;
      Zh[i * 72 + dd] = (f16)val;
      if (l == 2 && i == 0) zc[(size_t)b * 64 + dd] = val;
    }
    __syncthreads();
  }
}

// ---------------- ODE v2: 2 waves/block, split weight frags (no spill) ----------------
__global__ __launch_bounds__(128, 1) void ode_kernel(
    const char* __restrict__ wsb, const float* __restrict__ zc,
    float* __restrict__ out) {
  const f16* dr1h = (const f16*)(wsb);
  const f16* tau1h = (const f16*)(wsb + 16384);
  const f16* Ah = (const f16*)(wsb + 65536);
  const f16* fch = (const f16*)(wsb + 73728);
  const float* fb = (const float*)(wsb + 98304);

  __shared__ __align__(16) f16 dr2s[64 * 128];
  __shared__ __align__(16) f16 tau2s[64 * 128];
  __shared__ __align__(16) f16 ztL[16 * 64];
  __shared__ __align__(16) f16 hdL[16 * 128];
  __shared__ __align__(16) f16 htL[16 * 128];

  const int t = threadIdx.x;
  const int w = t >> 6;
  const int lane = t & 63;
  const int c16 = lane & 15, q4 = lane >> 4;
  const int b0 = blockIdx.x * 16;
  const int swz = (c16 & 7) << 3;

  // stage dr2/tau2 into LDS, XOR-swizzled 16B granules
  for (int i = t; i < 2048; i += 128) {
    int m = i >> 10, gi = i & 1023, row = gi >> 4, g = gi & 15;
    uint4 v = ((const uint4*)(wsb + 32768 + m * 16384))[gi];
    ((uint4*)(m ? tau2s : dr2s))[row * 16 + (g ^ (row & 7))] = v;
  }

  // per-wave weight fragments: hid-cols w*4+j (j<4), out-cols w*2+j (j<2)
  f16x8 dr1B[4][2], tau1B[4][2], AB[2][2];
#pragma unroll
  for (int j = 0; j < 4; ++j) {
    int cth = w * 4 + j;
#pragma unroll
    for (int kb = 0; kb < 2; ++kb) {
      dr1B[j][kb] = ld8(dr1h + (cth * 16 + c16) * 64 + kb * 32 + q4 * 8);
      tau1B[j][kb] = ld8(tau1h + (cth * 16 + c16) * 64 + kb * 32 + q4 * 8);
    }
  }
#pragma unroll
  for (int j = 0; j < 2; ++j) {
    int ctg = w * 2 + j;
#pragma unroll
    for (int kb = 0; kb < 2; ++kb)
      AB[j][kb] = ld8(Ah + (ctg * 16 + c16) * 64 + kb * 32 + q4 * 8);
  }
  float dr1b[4], tau1b[4], t1t[4];
#pragma unroll
  for (int j = 0; j < 4; ++j) {
    int cc = (w * 4 + j) * 16 + c16;
    dr1b[j] = fb[cc]; tau1b[j] = fb[128 + cc]; t1t[j] = fb[384 + cc];
  }
  float dr2b[2], tau2b[2];
#pragma unroll
  for (int j = 0; j < 2; ++j) {
    int cc = (w * 2 + j) * 16 + c16;
    dr2b[j] = fb[256 + cc]; tau2b[j] = fb[320 + cc];
  }

  // zt master (f32): wave w owns cols (w*2+j)*16+c16, rows q4*4+r
  float zt[2][4];
#pragma unroll
  for (int j = 0; j < 2; ++j)
#pragma unroll
    for (int r = 0; r < 4; ++r)
      zt[j][r] = zc[(size_t)(b0 + q4 * 4 + r) * 64 + (w * 2 + j) * 16 + c16];

  __syncthreads();

  float tm = 0.f;
  for (int s = 0; s < 32; ++s) {
#pragma unroll
    for (int j = 0; j < 2; ++j)
#pragma unroll
      for (int r = 0; r < 4; ++r) {
        int row = q4 * 4 + r;
        ztL[row * 64 + (((w * 2 + j) * 16 + c16) ^ ((row & 7) << 3))] = (f16)zt[j][r];
      }
    __syncthreads();
    f16x8 ztA[2];
#pragma unroll
    for (int kb = 0; kb < 2; ++kb)
      ztA[kb] = ld8(ztL + c16 * 64 + ((kb * 32 + q4 * 8) ^ swz));

    // phase 1: hidden layers (wave w does 4 of 8 col-tiles)
#pragma unroll
    for (int j = 0; j < 4; ++j) {
      f32x4 ad = {}, at = {};
      ad = mfma32(ztA[0], dr1B[j][0], ad);
      ad = mfma32(ztA[1], dr1B[j][1], ad);
      at = mfma32(ztA[0], tau1B[j][0], at);
      at = mfma32(ztA[1], tau1B[j][1], at);
      float bt = fmaf(tm, t1t[j], tau1b[j]);
      int colbase = (w * 4 + j) * 16 + c16;
#pragma unroll
      for (int r = 0; r < 4; ++r) {
        int row = q4 * 4 + r;
        int off = row * 128 + (colbase ^ ((row & 7) << 3));
        hdL[off] = (f16)ftanh(ad[r] + dr1b[j]);
        htL[off] = (f16)ftanh(at[r] + bt);
      }
    }
    __syncthreads();
    f16x8 hdA[4], htA[4];
#pragma unroll
    for (int kb = 0; kb < 4; ++kb) {
      int ko = c16 * 128 + ((kb * 32 + q4 * 8) ^ swz);
      hdA[kb] = ld8(hdL + ko);
      htA[kb] = ld8(htL + ko);
    }

    // phase 2: drive/tau/zA + Euler (wave w does 2 of 4 col-tiles)
#pragma unroll
    for (int j = 0; j < 2; ++j) {
      int row16 = ((w * 2 + j) * 16 + c16) * 128;
      f32x4 dv = {}, tr = {}, za = {};
#pragma unroll
      for (int kb = 0; kb < 4; ++kb) {
        f16x8 bd = ld8(dr2s + row16 + ((kb * 32 + q4 * 8) ^ swz));
        f16x8 bt2 = ld8(tau2s + row16 + ((kb * 32 + q4 * 8) ^ swz));
        dv = mfma32(hdA[kb], bd, dv);
        tr = mfma32(htA[kb], bt2, tr);
      }
      za = mfma32(ztA[0], AB[j][0], za);
      za = mfma32(ztA[1], AB[j][1], za);
#pragma unroll
      for (int r = 0; r < 4; ++r) {
        float traw = tr[r] + tau2b[j];
        float sp = (traw > 15.f) ? traw : log1pf(__expf(traw));
        float sg = 1.f / (1.f + __expf(-(sp + 1e-6f)));
        float inv = 1.f / fmaf(4.95f, sg, 0.05f);
        float ztv = zt[j][r];
        float dz = za[r] + inv * ((dv[r] + dr2b[j]) - ztv);
        zt[j][r] = fmaf(0.03125f, dz, ztv);
      }
    }
    tm += 0.03125f;
  }

  // final FC (fused): wave w does 6 of 12 col-tiles
#pragma unroll
  for (int j = 0; j < 2; ++j)
#pragma unroll
    for (int r = 0; r < 4; ++r) {
      int row = q4 * 4 + r;
      ztL[row * 64 + (((w * 2 + j) * 16 + c16) ^ ((row & 7) << 3))] = (f16)zt[j][r];
    }
  __syncthreads();
  f16x8 zA2[2];
#pragma unroll
  for (int kb = 0; kb < 2; ++kb)
    zA2[kb] = ld8(ztL + c16 * 64 + ((kb * 32 + q4 * 8) ^ swz));
#pragma unroll
  for (int j = 0; j < 6; ++j) {
    int ct = w * 6 + j;
    f32x4 acc = {};
    acc = mfma32(zA2[0], ld8(fch + (ct * 16 + c16) * 64 + q4 * 8), acc);
    acc = mfma32(zA2[1], ld8(fch + (ct * 16 + c16) * 64 + 32 + q4 * 8), acc);
    float bias = fb[512 + ct * 16 + c16];
#pragma unroll
    for (int r = 0; r < 4; ++r)
      out[(size_t)(b0 + q4 * 4 + r) * 192 + ct * 16 + c16] = acc[r] + bias;
  }
}

extern "C" void kernel_launch(void* const* d_in, const int* in_sizes, int n_in,
                              void* d_out, int out_size, void* d_ws, size_t ws_size,
                              hipStream_t stream) {
  const float* x = (const float*)d_in[0];
  const float* conv_w = (const float*)d_in[1];
  const float* conv_b = (const float*)d_in[2];
  const float* cls = (const float*)d_in[3];
  const float* attn_w = (const float*)d_in[4];
  const float* attn_b = (const float*)d_in[5];
  const float* out_w = (const float*)d_in[6];
  const float* out_b = (const float*)d_in[7];
  const float* ln1_g = (const float*)d_in[8];
  const float* ln1_b = (const float*)d_in[9];
  const float* ln2_g = (const float*)d_in[10];
  const float* ln2_b = (const float*)d_in[11];
  const float* ff1_w = (const float*)d_in[12];
  const float* ff1_b = (const float*)d_in[13];
  const float* ff2_w = (const float*)d_in[14];
  const float* ff2_b = (const float*)d_in[15];
  const float* B_mat = (const float*)d_in[16];
  const float* dr1_w = (const float*)d_in[17];
  const float* dr1_b = (const float*)d_in[18];
  const float* dr2_w = (const float*)d_in[19];
  const float* dr2_b = (const float*)d_in[20];
  const float* tau1_w = (const float*)d_in[21];
  const float* tau1_b = (const float*)d_in[22];
  const float* tau2_w = (const float*)d_in[23];
  const float* tau2_b = (const float*)d_in[24];
  const float* fc_w = (const float*)d_in[25];
  const float* fc_b = (const float*)d_in[26];

  char* wsb = (char*)d_ws;
  float* zcb = (float*)(wsb + 101376);   // 4096*64 f32
  f16* tfw = (f16*)(wsb + 1149952);      // tf f16 weights (188416 B)

  prep_kernel<<<130, 64, 0, stream>>>(B_mat, dr1_w, dr1_b, dr2_w, dr2_b,
                                      tau1_w, tau1_b, tau2_w, tau2_b,
                                      fc_w, fc_b, wsb);
  prep_tf<<<368, 256, 0, stream>>>(conv_w, attn_w, out_w, ff1_w, ff2_w, tfw);
  tf_kernel<<<4096, 256, 0, stream>>>(x, tfw, conv_b, cls, attn_b, out_b,
                                      ln1_g, ln1_b, ln2_g, ln2_b, ff1_b, ff2_b, zcb);
  ode_kernel<<<256, 128, 0, stream>>>(wsb, zcb, (float*)d_out);
}

// Round 8
// 518.855 us; speedup vs baseline: 14.0730x; 1.0407x over previous
//
#include <hip/hip_runtime.h>
#include <hip/hip_fp16.h>
#include <math.h>

#define DEV static __device__ __forceinline__

typedef _Float16 f16;
typedef __attribute__((ext_vector_type(4))) _Float16 f16x4;
typedef __attribute__((ext_vector_type(8))) _Float16 f16x8;
typedef __attribute__((ext_vector_type(4))) float f32x4;

DEV f16x8 ld8(const f16* p) { return *(const f16x8*)p; }
DEV f32x4 mfma32(f16x8 a, f16x8 b, f32x4 c) {
  return __builtin_amdgcn_mfma_f32_16x16x32_f16(a, b, c, 0, 0, 0);
}
DEV float ftanh(float x) {
  float e = __expf(2.f * x);
  return 1.f - 2.f / (e + 1.f);
}

// ---------------- prep: pack ODE+FC weights f16 row-major [out][in] ----------------
__global__ __launch_bounds__(64) void prep_kernel(
    const float* __restrict__ Bm,
    const float* __restrict__ dr1_w, const float* __restrict__ dr1_b,
    const float* __restrict__ dr2_w, const float* __restrict__ dr2_b,
    const float* __restrict__ tau1_w, const float* __restrict__ tau1_b,
    const float* __restrict__ tau2_w, const float* __restrict__ tau2_b,
    const float* __restrict__ fc_w, const float* __restrict__ fc_b,
    char* __restrict__ wsb) {
  f16* dr1h = (f16*)(wsb);
  f16* tau1h = (f16*)(wsb + 16384);
  f16* dr2h = (f16*)(wsb + 32768);
  f16* tau2h = (f16*)(wsb + 49152);
  f16* Ah = (f16*)(wsb + 65536);
  f16* fch = (f16*)(wsb + 73728);
  float* fb = (float*)(wsb + 98304);

  const int t = threadIdx.x, blk = blockIdx.x;
  if (blk < 16) {
    int row = blk * 4 + (t >> 4), c0 = 4 * (t & 15);
    float a0 = 0.f, a1 = 0.f, a2 = 0.f, a3 = 0.f;
    for (int m = 0; m < 64; ++m) {
      float br = Bm[m * 64 + row];
      a0 = fmaf(br, Bm[m * 64 + c0 + 0], a0);
      a1 = fmaf(br, Bm[m * 64 + c0 + 1], a1);
      a2 = fmaf(br, Bm[m * 64 + c0 + 2], a2);
      a3 = fmaf(br, Bm[m * 64 + c0 + 3], a3);
    }
    Ah[row * 64 + c0 + 0] = (f16)(-a0);
    Ah[row * 64 + c0 + 1] = (f16)(-a1);
    Ah[row * 64 + c0 + 2] = (f16)(-a2);
    Ah[row * 64 + c0 + 3] = (f16)(-a3);
  } else if (blk < 48) {
    int idx = (blk - 16) * 64 + t;
    int row = idx >> 4, c0 = 4 * (idx & 15);
#pragma unroll
    for (int j = 0; j < 4; ++j) {
      dr1h[row * 64 + c0 + j] = (f16)dr1_w[row * 64 + c0 + j];
      tau1h[row * 64 + c0 + j] = (f16)tau1_w[row * 65 + c0 + j];
    }
  } else if (blk < 80) {
    int idx = (blk - 48) * 64 + t;
    int row = idx >> 5, c0 = 4 * (idx & 31);
#pragma unroll
    for (int j = 0; j < 4; ++j) {
      dr2h[row * 128 + c0 + j] = (f16)dr2_w[row * 128 + c0 + j];
      tau2h[row * 128 + c0 + j] = (f16)tau2_w[row * 128 + c0 + j];
    }
  } else if (blk < 128) {
    int idx = (blk - 80) * 64 + t;
    int row = idx >> 4, c0 = 4 * (idx & 15);
#pragma unroll
    for (int j = 0; j < 4; ++j)
      fch[row * 64 + c0 + j] = (f16)fc_w[row * 64 + c0 + j];
  } else {
    for (int i = (blk - 128) * 64 + t; i < 704; i += 128) {
      float v;
      if (i < 128) v = dr1_b[i];
      else if (i < 256) v = tau1_b[i - 128];
      else if (i < 320) v = dr2_b[i - 256];
      else if (i < 384) v = tau2_b[i - 320];
      else if (i < 512) v = tau1_w[(i - 384) * 65 + 64];
      else v = fc_b[i - 512];
      fb[i] = v;
    }
  }
}

// ---------------- prep_tf: tf weights -> f16 (unpadded row-major) + PE table -------
// tfw (f16): 0 CW[64][128] | per layer l at 8192 + l*28672:
//   +0 qkvW[192][64] | +12288 outW[64][64] | +16384 ff1W[96][64] | +22528 ff2W[64][96]
// pecb f32[32][64]: pos-enc rows 1..32 + conv_b
__global__ __launch_bounds__(256) void prep_tf(
    const float* __restrict__ conv_w, const float* __restrict__ attn_w,
    const float* __restrict__ out_w, const float* __restrict__ ff1_w,
    const float* __restrict__ ff2_w, const float* __restrict__ conv_b,
    f16* __restrict__ tfw, float* __restrict__ pecb) {
  int idx = blockIdx.x * 256 + threadIdx.x;
  if (idx >= 96256) return;
  if (idx >= 94208) {
    int e = idx - 94208;  // 0..2047
    int i = 1 + (e >> 6), dd = e & 63;
    float freq = __expf(-0.14391157f * (float)(dd & ~1));
    float ang = (float)i * freq;
    pecb[e] = ((dd & 1) ? cosf(ang) : sinf(ang)) + conv_b[dd];
    return;
  }
  float v;
  if (idx < 8192) {
    int dd = idx >> 7, k = idx & 127;
    v = conv_w[dd * 128 + (k & 7) * 16 + (k >> 3)];
  } else {
    int r = idx - 8192;
    int l = r / 28672, q = r - l * 28672;
    if (q < 12288) v = attn_w[l * 12288 + q];
    else if (q < 16384) v = out_w[l * 4096 + (q - 12288)];
    else if (q < 22528) v = ff1_w[l * 6144 + (q - 16384)];
    else v = ff2_w[l * 6144 + (q - 22528)];
  }
  tfw[idx] = (f16)v;
}

// ---------------- transformer: ROUND-5 structure + reg-hoisted weights + PE table --
// LDS (bytes): Zm f32[33][68] @0 | Zh f16[48][72] @8976 | Qh/oh @15888 | Kh @22800
//  | VT f16[64][56] @29712 | P f16[4][48][40] @36880 | psum @52240 | psq @53008
//  aliases: Sx f16[32][136] @15888 (prologue) ; f1h f16[48][104] @22800 (ff phase)
__global__ __launch_bounds__(256, 3) void tf_kernel(
    const float* __restrict__ x, const f16* __restrict__ tfw,
    const float* __restrict__ pecb, const float* __restrict__ cls,
    const float* __restrict__ attn_b, const float* __restrict__ out_b,
    const float* __restrict__ ln1_g, const float* __restrict__ ln1_b,
    const float* __restrict__ ln2_g, const float* __restrict__ ln2_b,
    const float* __restrict__ ff1_b, const float* __restrict__ ff2_b,
    float* __restrict__ zc) {
  __shared__ __align__(16) unsigned char SH[53776];
  float* Zm = (float*)SH;
  f16* Zh = (f16*)(SH + 8976);
  f16* Qh = (f16*)(SH + 15888);
  f16* Kh = (f16*)(SH + 22800);
  f16* VT = (f16*)(SH + 29712);
  f16* P = (f16*)(SH + 36880);
  float* psum = (float*)(SH + 52240);
  float* psq = (float*)(SH + 53008);
  f16* Sx = (f16*)(SH + 15888);
  f16* f1h = (f16*)(SH + 22800);
  f16* oh = Qh;

  const int t = threadIdx.x;
  const int b = blockIdx.x;
  const int w = t >> 6, lane = t & 63;
  const int c16 = lane & 15, q4 = lane >> 4;
  const int d = w * 16 + c16;

  // ---- prologue: x->Sx(f16), zero Zh pads + P, cls row (round-5 exact) ----
  {
    const float4* xg = (const float4*)(x + (size_t)b * 4096);
    for (int i = t; i < 1024; i += 256) {
      int n = i >> 5, jj = i & 31;
      float4 v = xg[i];
      *(f16x4*)(Sx + n * 136 + jj * 4) = f16x4{(f16)v.x, (f16)v.y, (f16)v.z, (f16)v.w};
    }
    unsigned* zp = (unsigned*)(Zh + 33 * 72);
    for (int i = t; i < 540; i += 256) zp[i] = 0u;
    uint4 z4{0, 0, 0, 0};
    uint4* pp = (uint4*)P;
    for (int i = t; i < 960; i += 256) pp[i] = z4;
    if (t < 64) {
      float v = cls[t] + ((t & 1) ? 1.0f : 0.0f);
      Zm[t] = v; Zh[t] = (f16)v;
    }
  }
  __syncthreads();

  // ---- patch embed (CW from L2) + PE table ----
  {
    f16x8 bw[4];
#pragma unroll
    for (int kb = 0; kb < 4; ++kb)
      bw[kb] = ld8(tfw + d * 128 + kb * 32 + q4 * 8);
#pragma unroll
    for (int rt = 0; rt < 2; ++rt) {
      f32x4 acc = {};
#pragma unroll
      for (int kb = 0; kb < 4; ++kb)
        acc = mfma32(ld8(Sx + (rt * 16 + c16) * 136 + kb * 32 + q4 * 8), bw[kb], acc);
#pragma unroll
      for (int r = 0; r < 4; ++r) {
        int zr = rt * 16 + q4 * 4 + r + 1;
        float val = acc[r] + pecb[(zr - 1) * 64 + d];
        Zm[zr * 68 + d] = val;
        Zh[zr * 72 + d] = (f16)val;
      }
    }
  }
  __syncthreads();

  for (int l = 0; l < 3; ++l) {
    const f16* lw = tfw + 8192 + l * 28672;
    const bool has2 = (w < 2);
    const int jj0 = d;
    const int jj1 = has2 ? (w + 4) * 16 + c16 : jj0;  // clamp for safe addr

    // ---- layer-resident weight fragments (loaded once per layer) ----
    f16x8 wq0 = ld8(lw + d * 64 + q4 * 8);
    f16x8 wq1 = ld8(lw + d * 64 + 32 + q4 * 8);
    f16x8 wk0 = ld8(lw + (64 + d) * 64 + q4 * 8);
    f16x8 wk1 = ld8(lw + (64 + d) * 64 + 32 + q4 * 8);
    f16x8 wv0 = ld8(lw + (128 + d) * 64 + q4 * 8);
    f16x8 wv1 = ld8(lw + (128 + d) * 64 + 32 + q4 * 8);
    f16x8 ow0 = ld8(lw + 12288 + d * 64 + q4 * 8);
    f16x8 ow1 = ld8(lw + 12288 + d * 64 + 32 + q4 * 8);
    f16x8 f1w00 = ld8(lw + 16384 + jj0 * 64 + q4 * 8);
    f16x8 f1w01 = ld8(lw + 16384 + jj0 * 64 + 32 + q4 * 8);
    f16x8 f1w10 = ld8(lw + 16384 + jj1 * 64 + q4 * 8);
    f16x8 f1w11 = ld8(lw + 16384 + jj1 * 64 + 32 + q4 * 8);
    f16x8 fw20 = ld8(lw + 22528 + d * 96 + q4 * 8);
    f16x8 fw21 = ld8(lw + 22528 + d * 96 + 32 + q4 * 8);
    f16x8 fw22 = ld8(lw + 22528 + d * 96 + 64 + q4 * 8);

    // ---- P1: qkv (round-5 math; weights from regs) ----
    {
      float bq = attn_b[l * 192 + d];
      float bk = attn_b[l * 192 + 64 + d];
      float bv = attn_b[l * 192 + 128 + d];
#pragma unroll
      for (int rt = 0; rt < 3; ++rt) {
        f16x8 a0 = ld8(Zh + (rt * 16 + c16) * 72 + q4 * 8);
        f16x8 a1 = ld8(Zh + (rt * 16 + c16) * 72 + 32 + q4 * 8);
        f32x4 aq = {}, ak = {}, av = {};
        aq = mfma32(a0, wq0, aq); aq = mfma32(a1, wq1, aq);
        ak = mfma32(a0, wk0, ak); ak = mfma32(a1, wk1, ak);
        av = mfma32(a0, wv0, av); av = mfma32(a1, wv1, av);
#pragma unroll
        for (int r = 0; r < 4; ++r) {
          int i = rt * 16 + q4 * 4 + r;
          Qh[i * 72 + d] = (f16)((aq[r] + bq) * 0.25f);
          Kh[i * 72 + d] = (f16)(ak[r] + bk);
        }
        if (rt < 2) {
          *(f16x4*)(VT + d * 56 + rt * 16 + q4 * 4) =
              f16x4{(f16)(av[0] + bv), (f16)(av[1] + bv),
                    (f16)(av[2] + bv), (f16)(av[3] + bv)};
        } else if (q4 == 0) {
          VT[d * 56 + 32] = (f16)(av[0] + bv);
        }
      }
    }

    // ---- P2: scores + softmax + PV (round-5 exact, wave-private) ----
    {
      f16x8 zf = {};
      f16x8 aq[3], bkk[3];
#pragma unroll
      for (int rt = 0; rt < 3; ++rt)
        aq[rt] = (q4 < 2) ? ld8(Qh + (rt * 16 + c16) * 72 + w * 16 + q4 * 8) : zf;
#pragma unroll
      for (int ck = 0; ck < 3; ++ck)
        bkk[ck] = (q4 < 2) ? ld8(Kh + (ck * 16 + c16) * 72 + w * 16 + q4 * 8) : zf;
      f32x4 s[3][3];
#pragma unroll
      for (int rt = 0; rt < 3; ++rt)
#pragma unroll
        for (int ck = 0; ck < 3; ++ck) {
          f32x4 zz = {};
          s[rt][ck] = mfma32(aq[rt], bkk[ck], zz);
        }
      f16* Ph = P + w * 1920;
#pragma unroll
      for (int rt = 0; rt < 3; ++rt) {
#pragma unroll
        for (int r = 0; r < 4; ++r) {
          int i = rt * 16 + q4 * 4 + r;
          float v0 = s[rt][0][r], v1 = s[rt][1][r];
          float v2 = (c16 == 0) ? s[rt][2][r] : -1e30f;
          float m = fmaxf(fmaxf(v0, v1), v2);
          m = fmaxf(m, __shfl_xor(m, 1));
          m = fmaxf(m, __shfl_xor(m, 2));
          m = fmaxf(m, __shfl_xor(m, 4));
          m = fmaxf(m, __shfl_xor(m, 8));
          float e0 = __expf(v0 - m), e1 = __expf(v1 - m);
          float e2 = (c16 == 0) ? __expf(v2 - m) : 0.f;
          float su = e0 + e1 + e2;
          su += __shfl_xor(su, 1); su += __shfl_xor(su, 2);
          su += __shfl_xor(su, 4); su += __shfl_xor(su, 8);
          float inv = 1.f / su;
          if (i < 33) {
            Ph[i * 40 + c16] = (f16)(e0 * inv);
            Ph[i * 40 + 16 + c16] = (f16)(e1 * inv);
            if (c16 == 0) Ph[i * 40 + 32] = (f16)(e2 * inv);
          }
        }
      }
      f16x8 bv = ld8(VT + d * 56 + q4 * 8);
      float v32 = (float)VT[d * 56 + 32];
#pragma unroll
      for (int rt = 0; rt < 3; ++rt) {
        f32x4 acc = {};
        acc = mfma32(ld8(Ph + (rt * 16 + c16) * 40 + q4 * 8), bv, acc);
#pragma unroll
        for (int r = 0; r < 4; ++r) {
          int i = rt * 16 + q4 * 4 + r;
          oh[i * 72 + d] = (f16)(acc[r] + (float)Ph[i * 40 + 32] * v32);
        }
      }
    }
    __syncthreads();

    // ---- P3: out-proj + residual + LN1 partials (weights from regs) ----
    {
      float bias = out_b[l * 64 + d];
#pragma unroll
      for (int rt = 0; rt < 3; ++rt) {
        f32x4 acc = {};
        acc = mfma32(ld8(oh + (rt * 16 + c16) * 72 + q4 * 8), ow0, acc);
        acc = mfma32(ld8(oh + (rt * 16 + c16) * 72 + 32 + q4 * 8), ow1, acc);
#pragma unroll
        for (int r = 0; r < 4; ++r) {
          int i = rt * 16 + q4 * 4 + r;
          float val = 0.f;
          if (i < 33) {
            val = Zm[i * 68 + d] + acc[r] + bias;
            Zm[i * 68 + d] = val;
          }
          float vs = val, vq = val * val;
          vs += __shfl_xor(vs, 1); vq += __shfl_xor(vq, 1);
          vs += __shfl_xor(vs, 2); vq += __shfl_xor(vq, 2);
          vs += __shfl_xor(vs, 4); vq += __shfl_xor(vq, 4);
          vs += __shfl_xor(vs, 8); vq += __shfl_xor(vq, 8);
          if (c16 == 0 && i < 33) { psum[w * 48 + i] = vs; psq[w * 48 + i] = vq; }
        }
      }
    }
    __syncthreads();

    // ---- P4: norm1 ----
    for (int idx = t; idx < 2112; idx += 256) {
      int i = idx >> 6, dd = idx & 63;
      float m = (psum[i] + psum[48 + i] + psum[96 + i] + psum[144 + i]) * 0.015625f;
      float sq = (psq[i] + psq[48 + i] + psq[96 + i] + psq[144 + i]) * 0.015625f;
      float rr = rsqrtf(sq - m * m + 1e-5f);
      float val = (Zm[i * 68 + dd] - m) * rr * ln1_g[l * 64 + dd] + ln1_b[l * 64 + dd];
      Zm[i * 68 + dd] = val;
      Zh[i * 72 + dd] = (f16)val;
    }
    __syncthreads();

    // ---- P5: ff1 (round-5 tile assignment; weights from regs) ----
    {
      f16x8 a0[3], a1[3];
#pragma unroll
      for (int rt = 0; rt < 3; ++rt) {
        a0[rt] = ld8(Zh + (rt * 16 + c16) * 72 + q4 * 8);
        a1[rt] = ld8(Zh + (rt * 16 + c16) * 72 + 32 + q4 * 8);
      }
      float b0f = ff1_b[l * 96 + jj0];
#pragma unroll
      for (int rt = 0; rt < 3; ++rt) {
        f32x4 acc = {};
        acc = mfma32(a0[rt], f1w00, acc);
        acc = mfma32(a1[rt], f1w01, acc);
#pragma unroll
        for (int r = 0; r < 4; ++r)
          f1h[(rt * 16 + q4 * 4 + r) * 104 + jj0] = (f16)fmaxf(acc[r] + b0f, 0.f);
      }
      if (has2) {
        float b1f = ff1_b[l * 96 + jj1];
#pragma unroll
        for (int rt = 0; rt < 3; ++rt) {
          f32x4 acc = {};
          acc = mfma32(a0[rt], f1w10, acc);
          acc = mfma32(a1[rt], f1w11, acc);
#pragma unroll
          for (int r = 0; r < 4; ++r)
            f1h[(rt * 16 + q4 * 4 + r) * 104 + jj1] = (f16)fmaxf(acc[r] + b1f, 0.f);
        }
      }
    }
    __syncthreads();

    // ---- P6: ff2 + residual + LN2 partials (weights from regs) ----
    {
      float bias = ff2_b[l * 64 + d];
#pragma unroll
      for (int rt = 0; rt < 3; ++rt) {
        f32x4 acc = {};
        acc = mfma32(ld8(f1h + (rt * 16 + c16) * 104 + q4 * 8), fw20, acc);
        acc = mfma32(ld8(f1h + (rt * 16 + c16) * 104 + 32 + q4 * 8), fw21, acc);
        acc = mfma32(ld8(f1h + (rt * 16 + c16) * 104 + 64 + q4 * 8), fw22, acc);
#pragma unroll
        for (int r = 0; r < 4; ++r) {
          int i = rt * 16 + q4 * 4 + r;
          float val = 0.f;
          if (i < 33) {
            val = Zm[i * 68 + d] + acc[r] + bias;
            Zm[i * 68 + d] = val;
          }
          float vs = val, vq = val * val;
          vs += __shfl_xor(vs, 1); vq += __shfl_xor(vq, 1);
          vs += __shfl_xor(vs, 2); vq += __shfl_xor(vq, 2);
          vs += __shfl_xor(vs, 4); vq += __shfl_xor(vq, 4);
          vs += __shfl_xor(vs, 8); vq += __shfl_xor(vq, 8);
          if (c16 == 0 && i < 33) { psum[w * 48 + i] = vs; psq[w * 48 + i] = vq; }
        }
      }
    }
    __syncthreads();

    // ---- P7: norm2 (+ zc on last layer) ----
    for (int idx = t; idx < 2112; idx += 256) {
      int i = idx >> 6, dd = idx & 63;
      float m = (psum[i] + psum[48 + i] + psum[96 + i] + psum[144 + i]) * 0.015625f;
      float sq = (psq[i] + psq[48 + i] + psq[96 + i] + psq[144 + i]) * 0.015625f;
      float rr = rsqrtf(sq - m * m + 1e-5f);
      float val = (Zm[i * 68 + dd] - m) * rr * ln2_g[l * 64 + dd] + ln2_b[l * 64 + dd];
      Zm[i * 68 + dd] = val;
      Zh[i * 72 + dd] = (f16)val;
      if (l == 2 && i == 0) zc[(size_t)b * 64 + dd] = val;
    }
    __syncthreads();
  }
}

// ---------------- ODE v2 (unchanged, known-good) ----------------
__global__ __launch_bounds__(128, 1) void ode_kernel(
    const char* __restrict__ wsb, const float* __restrict__ zc,
    float* __restrict__ out) {
  const f16* dr1h = (const f16*)(wsb);
  const f16* tau1h = (const f16*)(wsb + 16384);
  const f16* Ah = (const f16*)(wsb + 65536);
  const f16* fch = (const f16*)(wsb + 73728);
  const float* fb = (const float*)(wsb + 98304);

  __shared__ __align__(16) f16 dr2s[64 * 128];
  __shared__ __align__(16) f16 tau2s[64 * 128];
  __shared__ __align__(16) f16 ztL[16 * 64];
  __shared__ __align__(16) f16 hdL[16 * 128];
  __shared__ __align__(16) f16 htL[16 * 128];

  const int t = threadIdx.x;
  const int w = t >> 6;
  const int lane = t & 63;
  const int c16 = lane & 15, q4 = lane >> 4;
  const int b0 = blockIdx.x * 16;
  const int swz = (c16 & 7) << 3;

  for (int i = t; i < 2048; i += 128) {
    int m = i >> 10, gi = i & 1023, row = gi >> 4, g = gi & 15;
    uint4 v = ((const uint4*)(wsb + 32768 + m * 16384))[gi];
    ((uint4*)(m ? tau2s : dr2s))[row * 16 + (g ^ (row & 7))] = v;
  }

  f16x8 dr1B[4][2], tau1B[4][2], AB[2][2];
#pragma unroll
  for (int j = 0; j < 4; ++j) {
    int cth = w * 4 + j;
#pragma unroll
    for (int kb = 0; kb < 2; ++kb) {
      dr1B[j][kb] = ld8(dr1h + (cth * 16 + c16) * 64 + kb * 32 + q4 * 8);
      tau1B[j][kb] = ld8(tau1h + (cth * 16 + c16) * 64 + kb * 32 + q4 * 8);
    }
  }
#pragma unroll
  for (int j = 0; j < 2; ++j) {
    int ctg = w * 2 + j;
#pragma unroll
    for (int kb = 0; kb < 2; ++kb)
      AB[j][kb] = ld8(Ah + (ctg * 16 + c16) * 64 + kb * 32 + q4 * 8);
  }
  float dr1b[4], tau1b[4], t1t[4];
#pragma unroll
  for (int j = 0; j < 4; ++j) {
    int cc = (w * 4 + j) * 16 + c16;
    dr1b[j] = fb[cc]; tau1b[j] = fb[128 + cc]; t1t[j] = fb[384 + cc];
  }
  float dr2b[2], tau2b[2];
#pragma unroll
  for (int j = 0; j < 2; ++j) {
    int cc = (w * 2 + j) * 16 + c16;
    dr2b[j] = fb[256 + cc]; tau2b[j] = fb[320 + cc];
  }

  float zt[2][4];
#pragma unroll
  for (int j = 0; j < 2; ++j)
#pragma unroll
    for (int r = 0; r < 4; ++r)
      zt[j][r] = zc[(size_t)(b0 + q4 * 4 + r) * 64 + (w * 2 + j) * 16 + c16];

  __syncthreads();

  float tm = 0.f;
  for (int s = 0; s < 32; ++s) {
#pragma unroll
    for (int j = 0; j < 2; ++j)
#pragma unroll
      for (int r = 0; r < 4; ++r) {
        int row = q4 * 4 + r;
        ztL[row * 64 + (((w * 2 + j) * 16 + c16) ^ ((row & 7) << 3))] = (f16)zt[j][r];
      }
    __syncthreads();
    f16x8 ztA[2];
#pragma unroll
    for (int kb = 0; kb < 2; ++kb)
      ztA[kb] = ld8(ztL + c16 * 64 + ((kb * 32 + q4 * 8) ^ swz));

#pragma unroll
    for (int j = 0; j < 4; ++j) {
      f32x4 ad = {}, at = {};
      ad = mfma32(ztA[0], dr1B[j][0], ad);
      ad = mfma32(ztA[1], dr1B[j][1], ad);
      at = mfma32(ztA[0], tau1B[j][0], at);
      at = mfma32(ztA[1], tau1B[j][1], at);
      float bt = fmaf(tm, t1t[j], tau1b[j]);
      int colbase = (w * 4 + j) * 16 + c16;
#pragma unroll
      for (int r = 0; r < 4; ++r) {
        int row = q4 * 4 + r;
        int off = row * 128 + (colbase ^ ((row & 7) << 3));
        hdL[off] = (f16)ftanh(ad[r] + dr1b[j]);
        htL[off] = (f16)ftanh(at[r] + bt);
      }
    }
    __syncthreads();
    f16x8 hdA[4], htA[4];
#pragma unroll
    for (int kb = 0; kb < 4; ++kb) {
      int ko = c16 * 128 + ((kb * 32 + q4 * 8) ^ swz);
      hdA[kb] = ld8(hdL + ko);
      htA[kb] = ld8(htL + ko);
    }

#pragma unroll
    for (int j = 0; j < 2; ++j) {
      int row16 = ((w * 2 + j) * 16 + c16) * 128;
      f32x4 dv = {}, tr = {}, za = {};
#pragma unroll
      for (int kb = 0; kb < 4; ++kb) {
        f16x8 bd = ld8(dr2s + row16 + ((kb * 32 + q4 * 8) ^ swz));
        f16x8 bt2 = ld8(tau2s + row16 + ((kb * 32 + q4 * 8) ^ swz));
        dv = mfma32(hdA[kb], bd, dv);
        tr = mfma32(htA[kb], bt2, tr);
      }
      za = mfma32(ztA[0], AB[j][0], za);
      za = mfma32(ztA[1], AB[j][1], za);
#pragma unroll
      for (int r = 0; r < 4; ++r) {
        float traw = tr[r] + tau2b[j];
        float sp = (traw > 15.f) ? traw : log1pf(__expf(traw));
        float sg = 1.f / (1.f + __expf(-(sp + 1e-6f)));
        float inv = 1.f / fmaf(4.95f, sg, 0.05f);
        float ztv = zt[j][r];
        float dz = za[r] + inv * ((dv[r] + dr2b[j]) - ztv);
        zt[j][r] = fmaf(0.03125f, dz, ztv);
      }
    }
    tm += 0.03125f;
  }

#pragma unroll
  for (int j = 0; j < 2; ++j)
#pragma unroll
    for (int r = 0; r < 4; ++r) {
      int row = q4 * 4 + r;
      ztL[row * 64 + (((w * 2 + j) * 16 + c16) ^ ((row & 7) << 3))] = (f16)zt[j][r];
    }
  __syncthreads();
  f16x8 zA2[2];
#pragma unroll
  for (int kb = 0; kb < 2; ++kb)
    zA2[kb] = ld8(ztL + c16 * 64 + ((kb * 32 + q4 * 8) ^ swz));
#pragma unroll
  for (int j = 0; j < 6; ++j) {
    int ct = w * 6 + j;
    f32x4 acc = {};
    acc = mfma32(zA2[0], ld8(fch + (ct * 16 + c16) * 64 + q4 * 8), acc);
    acc = mfma32(zA2[1], ld8(fch + (ct * 16 + c16) * 64 + 32 + q4 * 8), acc);
    float bias = fb[512 + ct * 16 + c16];
#pragma unroll
    for (int r = 0; r < 4; ++r)
      out[(size_t)(b0 + q4 * 4 + r) * 192 + ct * 16 + c16] = acc[r] + bias;
  }
}

extern "C" void kernel_launch(void* const* d_in, const int* in_sizes, int n_in,
                              void* d_out, int out_size, void* d_ws, size_t ws_size,
                              hipStream_t stream) {
  const float* x = (const float*)d_in[0];
  const float* conv_w = (const float*)d_in[1];
  const float* conv_b = (const float*)d_in[2];
  const float* cls = (const float*)d_in[3];
  const float* attn_w = (const float*)d_in[4];
  const float* attn_b = (const float*)d_in[5];
  const float* out_w = (const float*)d_in[6];
  const float* out_b = (const float*)d_in[7];
  const float* ln1_g = (const float*)d_in[8];
  const float* ln1_b = (const float*)d_in[9];
  const float* ln2_g = (const float*)d_in[10];
  const float* ln2_b = (const float*)d_in[11];
  const float* ff1_w = (const float*)d_in[12];
  const float* ff1_b = (const float*)d_in[13];
  const float* ff2_w = (const float*)d_in[14];
  const float* ff2_b = (const float*)d_in[15];
  const float* B_mat = (const float*)d_in[16];
  const float* dr1_w = (const float*)d_in[17];
  const float* dr1_b = (const float*)d_in[18];
  const float* dr2_w = (const float*)d_in[19];
  const float* dr2_b = (const float*)d_in[20];
  const float* tau1_w = (const float*)d_in[21];
  const float* tau1_b = (const float*)d_in[22];
  const float* tau2_w = (const float*)d_in[23];
  const float* tau2_b = (const float*)d_in[24];
  const float* fc_w = (const float*)d_in[25];
  const float* fc_b = (const float*)d_in[26];

  char* wsb = (char*)d_ws;
  float* zcb = (float*)(wsb + 101376);     // 4096*64 f32
  f16* tfw = (f16*)(wsb + 1149952);        // 188416 B
  float* pecb = (float*)(wsb + 1338368);   // 8192 B

  prep_kernel<<<130, 64, 0, stream>>>(B_mat, dr1_w, dr1_b, dr2_w, dr2_b,
                                      tau1_w, tau1_b, tau2_w, tau2_b,
                                      fc_w, fc_b, wsb);
  prep_tf<<<376, 256, 0, stream>>>(conv_w, attn_w, out_w, ff1_w, ff2_w, conv_b,
                                   tfw, pecb);
  tf_kernel<<<4096, 256, 0, stream>>>(x, tfw, pecb, cls, attn_b, out_b,
                                      ln1_g, ln1_b, ln2_g, ln2_b, ff1_b, ff2_b, zcb);
  ode_kernel<<<256, 128, 0, stream>>>(wsb, zcb, (float*)d_out);
}